// Round 9
// baseline (352.381 us; speedup 1.0000x reference)
//
#include <hip/hip_runtime.h>

// 3-layer GCN + mean pool. R22: selector-MFMA aggregation, hardened.
// R21 failed correctness (absmax 0.324 ~ a few nodes misaggregated).
// MFMA conventions are provably safe (shared-k-permutation invariance +
// pairings identical to the verified GEMM phase), so the suspects were
// the hand-rolled serial S-fill and stale-LDS M slots. Both replaced by
// patterns already verified on HW:
//  - col[e] packs src(18b) | (dst&15)<<26 (R17's packing, passed) ->
//    S filled per-SLOT by one thread reading the owner from col. Single
//    writer, no bounds arithmetic. +1 barrier/chunk (zero->fill order).
//  - M slots with no valid row are ZERO-FILLED (always-store).
// Rest identical to R21: agg[16xK] = S[16x64] x M[64xK] on the matrix
// pipe, bf16 interchange, 16-node/256-thread blocks.

#define DIN 30
#define HD  128

typedef __attribute__((ext_vector_type(8))) short v8s;
typedef __attribute__((ext_vector_type(4))) float v4f;

static __device__ __forceinline__ unsigned short f2bf(float f) {
  unsigned int u = __float_as_uint(f);
  u += 0x7fffu + ((u >> 16) & 1u);   // RNE
  return (unsigned short)(u >> 16);
}
static __device__ __forceinline__ float bf2f(unsigned short s) {
  return __uint_as_float(((unsigned int)s) << 16);
}

// ---------------- preprocessing ----------------
__global__ void k_degree(const int* __restrict__ dst, int* __restrict__ deg,
                         int* __restrict__ eord, int E) {
  int e = blockIdx.x * blockDim.x + threadIdx.x;
  if (e < E) eord[e] = atomicAdd(&deg[dst[e]], 1);
}

// single-dispatch exclusive scan (decoupled lookback, flag bit 31) + dinv.
__global__ void k_scan(const int* __restrict__ deg, int* __restrict__ scanbuf,
                       int* __restrict__ rowptr, float* __restrict__ dinv, int N) {
  __shared__ int s[256];
  __shared__ int sbase;
  int bid = blockIdx.x, tid = threadIdx.x;
  int base = bid * 1024 + tid * 4;
  int v[4]; int t = 0;
#pragma unroll
  for (int j = 0; j < 4; ++j) { int idx = base + j; v[j] = (idx < N) ? deg[idx] : 0; t += v[j]; }
  s[tid] = t; __syncthreads();
  for (int d = 1; d < 256; d <<= 1) {
    int u = (tid >= d) ? s[tid - d] : 0;
    __syncthreads();
    s[tid] += u;
    __syncthreads();
  }
  int myexcl = s[tid] - t;
  int blocktotal = s[255];
  if (tid == 0) atomicExch(&scanbuf[bid], blocktotal | 0x80000000);

  int pre = 0;
  for (int p = tid; p < bid; p += 256) {
    int val;
    do { val = atomicAdd(&scanbuf[p], 0); } while (!(val & 0x80000000));
    pre += val & 0x7fffffff;
  }
  __syncthreads();
  s[tid] = pre; __syncthreads();
  for (int d = 128; d > 0; d >>= 1) { if (tid < d) s[tid] += s[tid + d]; __syncthreads(); }
  if (tid == 0) sbase = s[0];
  __syncthreads();

  int run = sbase + myexcl;
#pragma unroll
  for (int j = 0; j < 4; ++j) {
    int idx = base + j;
    if (idx < N) {
      rowptr[idx] = run;
      dinv[idx] = rsqrtf((float)(1 + v[j]));
    }
    run += v[j];
    if (idx == N - 1) rowptr[N] = run;
  }
}

// fragment-major weight pack helper
static __device__ __forceinline__ void wtf_one(const float* __restrict__ W,
                                               unsigned short* __restrict__ WTF,
                                               int idx, int Kreal, int KK) {
  int j = idx & 7;
  int c = idx >> 3;
  int l15 = c & 15;
  int quad = (c >> 4) & 3;
  int kk = (c >> 6) % KK;
  int t = c / (64 * KK);
  int k = kk * 32 + quad * 8 + j;
  int n = t * 16 + l15;
  WTF[idx] = (k < Kreal) ? f2bf(W[k * 128 + n]) : (unsigned short)0;
}

// merged prep: packed CSR scatter | xcast | wtf | bounds | out-zero
__global__ void k_prep(const int* __restrict__ src, const int* __restrict__ dst,
                       const int* __restrict__ rowptr, const int* __restrict__ eord,
                       unsigned int* __restrict__ col, int E,
                       const float* __restrict__ x, const float* __restrict__ dinv,
                       unsigned short* __restrict__ xb, int N,
                       const float* __restrict__ W1, const float* __restrict__ W2,
                       const float* __restrict__ W3,
                       unsigned short* __restrict__ W1F, unsigned short* __restrict__ W2F,
                       unsigned short* __restrict__ W3F,
                       const int* __restrict__ batch, int* __restrict__ gstart, int G,
                       float* __restrict__ out,
                       int SB, int XB, int WB, int BB) {
  int blk = blockIdx.x;
  if (blk < SB) {
    int e = blk * 256 + threadIdx.x;
    if (e < E) {
      int d = dst[e];
      // src in low 18 bits (N < 2^18), block-local owner (d & 15) at bit 26
      col[rowptr[d] + eord[e]] = (unsigned int)src[e] | ((unsigned int)(d & 15) << 26);
    }
  } else if (blk < SB + XB) {
    int idx = (blk - SB) * 256 + threadIdx.x;
    if (idx < N * 32) {
      int n = idx >> 5, f = idx & 31;
      float v = (f < DIN) ? x[(size_t)n * DIN + f] * dinv[n] : 0.f;
      xb[idx] = f2bf(v);
    }
  } else if (blk < SB + XB + WB) {
    int idx = (blk - SB - XB) * 256 + threadIdx.x;
    if (idx < 4096) wtf_one(W1, W1F, idx, DIN, 1);
    else if (idx < 20480) wtf_one(W2, W2F, idx - 4096, 128, 4);
    else if (idx < 36864) wtf_one(W3, W3F, idx - 20480, 128, 4);
  } else if (blk < SB + XB + WB + BB) {
    int i = (blk - SB - XB - WB) * 256 + threadIdx.x;
    if (i >= N) return;
    int b = batch[i];
    int prev = (i == 0) ? -1 : batch[i - 1];
    for (int g = prev + 1; g <= b; ++g) gstart[g] = i;
    if (i == N - 1)
      for (int g = b + 1; g <= G; ++g) gstart[g] = N;
  } else {
    int idx = (blk - SB - XB - WB - BB) * 256 + threadIdx.x;
    if (idx < G * 32)
      ((float4*)out)[idx] = make_float4(0.f, 0.f, 0.f, 0.f);
  }
}

// ---------------- fused selector-MFMA aggregate + GEMM (layers 1,2) ----------------
// 256 threads / 16 nodes. hin: bf16 rows of K feats. C out: bf16 N x 128.
template <int K>
__global__ __launch_bounds__(256, 6) void k_fused(const unsigned short* __restrict__ hin,
                                                  const unsigned short* __restrict__ WTF,
                                                  const float* __restrict__ bias,
                                                  const int* __restrict__ rowptr,
                                                  const unsigned int* __restrict__ col,
                                                  const float* __restrict__ dinv,
                                                  unsigned short* __restrict__ C, int N) {
  constexpr int KK = K / 32;          // A k-tiles in GEMM phase
  constexpr int NP = K / 16;          // 16-feat panels (agg output tiles)
  constexpr int MPB = (K + 8) * 2;    // M row byte pitch (16B-aligned)
  constexpr int KP = K + 8;           // sm pitch (ushorts)
  constexpr int SP = 72;              // S pitch (ushorts)
  constexpr int MB = 64 * MPB;
  constexpr int SMB = 16 * KP * 2;
  constexpr int BUFB = (MB > SMB) ? MB : SMB;
  __shared__ __align__(16) char buf[BUFB];
  __shared__ __align__(16) unsigned short S[16 * SP];
  char* M = buf;
  unsigned short* sm = (unsigned short*)buf;

  int tid = threadIdx.x;
  int l16 = tid & 15, g = tid >> 4;
  int lane = tid & 63, wv = tid >> 6, quad = lane >> 4, l15 = lane & 15;
  int row0 = blockIdx.x * 16;
  int rend = row0 + 16; if (rend > N) rend = N;
  int eb = rowptr[row0];
  int ee = rowptr[rend];
  int nchunks = (16 + (ee - eb) + 63) >> 6;

  v4f agg0 = {0.f, 0.f, 0.f, 0.f}, agg1 = {0.f, 0.f, 0.f, 0.f};

  for (int c = 0; c < nchunks; ++c) {
    int ebase = eb - 16 + c * 64;     // slot s <-> edge ebase+s (chunk0 s<16 = self)
    // zero S: each group zeroes its own row
    *(uint2*)&S[g * SP + l16 * 4] = make_uint2(0u, 0u);
    __syncthreads();
    // per-slot S fill: one thread per slot, single writer
    if (tid < 64) {
      if (c == 0 && tid < 16) {
        if (row0 + tid < N) S[tid * SP + tid] = 0x3f80;   // self, 1.0bf16
      } else {
        int e = ebase + tid;
        if (e < ee) {
          int go = (int)(col[e] >> 26);                    // owner node in block
          S[go * SP + tid] = 0x3f80;
        }
      }
    }
    // stage M: 64 slots x K bf16, 16B pieces, XOR-swizzled; zero-fill invalid
    constexpr int PPS = K / 8;                      // 16B pieces per slot
    constexpr int ROUNDS = (64 * PPS) / 256;
#pragma unroll
    for (int q = 0; q < ROUNDS; ++q) {
      int pid = q * 256 + tid;
      int slot = pid / PPS;
      int sub = pid % PPS;
      int f0 = sub * 8;
      int srow = -1;
      if (c == 0 && slot < 16) {
        if (row0 + slot < N) srow = row0 + slot;
      } else {
        int e = ebase + slot;
        if (e >= eb && e < ee) srow = (int)(col[e] & 0x03FFFFFFu);
      }
      uint4 v = make_uint4(0u, 0u, 0u, 0u);
      if (srow >= 0) v = *(const uint4*)&hin[(size_t)srow * K + f0];
      int byte = (slot * MPB + f0 * 2) ^ (((slot >> 3) & 3) << 5);
      *(uint4*)(M + byte) = v;
    }
    __syncthreads();
    // agg MFMAs: acc += S x M   (slot dim = 64 -> 2 kk steps)
    if (NP == 8 || wv < 2) {
      v8s s0 = *(const v8s*)&S[l15 * SP + quad * 8];
      v8s s1 = *(const v8s*)&S[l15 * SP + 32 + quad * 8];
      int t0 = (NP == 8) ? wv * 2 : wv;
#pragma unroll
      for (int kk = 0; kk < 2; ++kk) {
        v8s mv;
#pragma unroll
        for (int j = 0; j < 8; ++j) {
          int slot = kk * 32 + quad * 8 + j;
          int byte = (slot * MPB + (t0 * 16 + l15) * 2) ^ (((slot >> 3) & 3) << 5);
          mv[j] = *(const short*)(M + byte);
        }
        agg0 = __builtin_amdgcn_mfma_f32_16x16x32_bf16(kk ? s1 : s0, mv, agg0, 0, 0, 0);
      }
      if (NP == 8) {
        int t1 = wv * 2 + 1;
#pragma unroll
        for (int kk = 0; kk < 2; ++kk) {
          v8s mv;
#pragma unroll
          for (int j = 0; j < 8; ++j) {
            int slot = kk * 32 + quad * 8 + j;
            int byte = (slot * MPB + (t1 * 16 + l15) * 2) ^ (((slot >> 3) & 3) << 5);
            mv[j] = *(const short*)(M + byte);
          }
          agg1 = __builtin_amdgcn_mfma_f32_16x16x32_bf16(kk ? s1 : s0, mv, agg1, 0, 0, 0);
        }
      }
    }
    __syncthreads();
  }

  // dinv for this lane's 4 acc rows (shared by agg deposit and epilogue)
  int crow0 = row0 + quad * 4;
  float dr[4];
  if (crow0 + 3 < N) {
    float4 d4 = *(const float4*)&dinv[crow0];
    dr[0] = d4.x; dr[1] = d4.y; dr[2] = d4.z; dr[3] = d4.w;
  } else {
#pragma unroll
    for (int i = 0; i < 4; ++i) dr[i] = (crow0 + i < N) ? dinv[crow0 + i] : 0.f;
  }

  // deposit agg (x dinv) -> sm as bf16 A-tile (aliases M; barrier above covers)
  if (NP == 8) {
#pragma unroll
    for (int i = 0; i < 4; ++i) {
      sm[(quad * 4 + i) * KP + (wv * 2) * 16 + l15] = f2bf(agg0[i] * dr[i]);
      sm[(quad * 4 + i) * KP + (wv * 2 + 1) * 16 + l15] = f2bf(agg1[i] * dr[i]);
    }
  } else if (wv < 2) {
#pragma unroll
    for (int i = 0; i < 4; ++i)
      sm[(quad * 4 + i) * KP + wv * 16 + l15] = f2bf(agg0[i] * dr[i]);
  }
  __syncthreads();

  // GEMM: 4 waves x 2 t-tiles, A from sm, B from WTF
  v8s af[KK];
#pragma unroll
  for (int kk = 0; kk < KK; ++kk)
    af[kk] = *(const v8s*)&sm[l15 * KP + kk * 32 + quad * 8];

#pragma unroll
  for (int tt = 0; tt < 2; ++tt) {
    int t = wv * 2 + tt;
    v4f acc = {0.f, 0.f, 0.f, 0.f};
#pragma unroll
    for (int kk = 0; kk < KK; ++kk) {
      v8s bf = *(const v8s*)(WTF + (size_t)(((t * KK + kk) * 4 + quad) * 16 + l15) * 8);
      acc = __builtin_amdgcn_mfma_f32_16x16x32_bf16(af[kk], bf, acc, 0, 0, 0);
    }
    float bi = bias[t * 16 + l15];
#pragma unroll
    for (int i = 0; i < 4; ++i) {
      int r = crow0 + i;
      if (r < N) {
        float o = fmaxf(acc[i] + bi, 0.f) * dr[i];   // next-layer dinv folded
        C[(size_t)r * 128 + t * 16 + l15] = f2bf(o);
      }
    }
  }
}

// ---------------- layer 3: selector-MFMA aggregate + GEMM + pool ----------------
__global__ __launch_bounds__(256, 6) void k_fused_pool(const unsigned short* __restrict__ hin,
                                                       const unsigned short* __restrict__ WTF,
                                                       const float* __restrict__ bias,
                                                       const int* __restrict__ rowptr,
                                                       const unsigned int* __restrict__ col,
                                                       const float* __restrict__ dinv,
                                                       const int* __restrict__ batch,
                                                       float* __restrict__ out, int N) {
  constexpr int K = 128, KK = 4;
  constexpr int MPB = (K + 8) * 2;
  constexpr int KP = K + 8;
  constexpr int CP = 132;
  constexpr int SP = 72;
  constexpr int MB = 64 * MPB;
  constexpr int SMB = (16 * KP * 2 > 16 * CP * 2) ? 16 * KP * 2 : 16 * CP * 2;
  constexpr int BUFB = (MB > SMB) ? MB : SMB;
  __shared__ __align__(16) char buf[BUFB];
  __shared__ __align__(16) unsigned short S[16 * SP];
  __shared__ int sbatch[16];
  char* M = buf;
  unsigned short* sm = (unsigned short*)buf;

  int tid = threadIdx.x;
  int l16 = tid & 15, g = tid >> 4;
  int lane = tid & 63, wv = tid >> 6, quad = lane >> 4, l15 = lane & 15;
  int row0 = blockIdx.x * 16;
  if (tid < 16) sbatch[tid] = (row0 + tid < N) ? batch[row0 + tid] : -1;
  int rend = row0 + 16; if (rend > N) rend = N;
  int eb = rowptr[row0];
  int ee = rowptr[rend];
  int nchunks = (16 + (ee - eb) + 63) >> 6;

  v4f agg0 = {0.f, 0.f, 0.f, 0.f}, agg1 = {0.f, 0.f, 0.f, 0.f};

  for (int c = 0; c < nchunks; ++c) {
    int ebase = eb - 16 + c * 64;
    *(uint2*)&S[g * SP + l16 * 4] = make_uint2(0u, 0u);
    __syncthreads();
    if (tid < 64) {
      if (c == 0 && tid < 16) {
        if (row0 + tid < N) S[tid * SP + tid] = 0x3f80;
      } else {
        int e = ebase + tid;
        if (e < ee) {
          int go = (int)(col[e] >> 26);
          S[go * SP + tid] = 0x3f80;
        }
      }
    }
    constexpr int PPS = K / 8;
    constexpr int ROUNDS = (64 * PPS) / 256;
#pragma unroll
    for (int q = 0; q < ROUNDS; ++q) {
      int pid = q * 256 + tid;
      int slot = pid / PPS;
      int sub = pid % PPS;
      int f0 = sub * 8;
      int srow = -1;
      if (c == 0 && slot < 16) {
        if (row0 + slot < N) srow = row0 + slot;
      } else {
        int e = ebase + slot;
        if (e >= eb && e < ee) srow = (int)(col[e] & 0x03FFFFFFu);
      }
      uint4 v = make_uint4(0u, 0u, 0u, 0u);
      if (srow >= 0) v = *(const uint4*)&hin[(size_t)srow * K + f0];
      int byte = (slot * MPB + f0 * 2) ^ (((slot >> 3) & 3) << 5);
      *(uint4*)(M + byte) = v;
    }
    __syncthreads();
    {
      v8s s0 = *(const v8s*)&S[l15 * SP + quad * 8];
      v8s s1 = *(const v8s*)&S[l15 * SP + 32 + quad * 8];
      int t0 = wv * 2, t1 = wv * 2 + 1;
#pragma unroll
      for (int kk = 0; kk < 2; ++kk) {
        v8s mv;
#pragma unroll
        for (int j = 0; j < 8; ++j) {
          int slot = kk * 32 + quad * 8 + j;
          int byte = (slot * MPB + (t0 * 16 + l15) * 2) ^ (((slot >> 3) & 3) << 5);
          mv[j] = *(const short*)(M + byte);
        }
        agg0 = __builtin_amdgcn_mfma_f32_16x16x32_bf16(kk ? s1 : s0, mv, agg0, 0, 0, 0);
      }
#pragma unroll
      for (int kk = 0; kk < 2; ++kk) {
        v8s mv;
#pragma unroll
        for (int j = 0; j < 8; ++j) {
          int slot = kk * 32 + quad * 8 + j;
          int byte = (slot * MPB + (t1 * 16 + l15) * 2) ^ (((slot >> 3) & 3) << 5);
          mv[j] = *(const short*)(M + byte);
        }
        agg1 = __builtin_amdgcn_mfma_f32_16x16x32_bf16(kk ? s1 : s0, mv, agg1, 0, 0, 0);
      }
    }
    __syncthreads();
  }

  int crow0 = row0 + quad * 4;
  float dr[4];
  if (crow0 + 3 < N) {
    float4 d4 = *(const float4*)&dinv[crow0];
    dr[0] = d4.x; dr[1] = d4.y; dr[2] = d4.z; dr[3] = d4.w;
  } else {
#pragma unroll
    for (int i = 0; i < 4; ++i) dr[i] = (crow0 + i < N) ? dinv[crow0 + i] : 0.f;
  }

#pragma unroll
  for (int i = 0; i < 4; ++i) {
    sm[(quad * 4 + i) * KP + (wv * 2) * 16 + l15] = f2bf(agg0[i] * dr[i]);
    sm[(quad * 4 + i) * KP + (wv * 2 + 1) * 16 + l15] = f2bf(agg1[i] * dr[i]);
  }
  __syncthreads();

  v8s af[KK];
#pragma unroll
  for (int kk = 0; kk < KK; ++kk)
    af[kk] = *(const v8s*)&sm[l15 * KP + kk * 32 + quad * 8];
  __syncthreads();             // buf reused as C staging below

  unsigned short* smc = (unsigned short*)buf;
#pragma unroll
  for (int tt = 0; tt < 2; ++tt) {
    int t = wv * 2 + tt;
    v4f acc = {0.f, 0.f, 0.f, 0.f};
#pragma unroll
    for (int kk = 0; kk < KK; ++kk) {
      v8s bf = *(const v8s*)(WTF + (size_t)(((t * KK + kk) * 4 + quad) * 16 + l15) * 8);
      acc = __builtin_amdgcn_mfma_f32_16x16x32_bf16(af[kk], bf, acc, 0, 0, 0);
    }
    float bi = bias[t * 16 + l15];
#pragma unroll
    for (int i = 0; i < 4; ++i) {
      float o = fmaxf(acc[i] + bi, 0.f);          // raw h3 for pooling
      smc[(quad * 4 + i) * CP + t * 16 + l15] = f2bf(o);
    }
  }
  __syncthreads();

  // segment-sum the 16 sorted rows, atomicAdd partials
  int f = tid & 127;
  int grp = tid >> 7;          // 2 groups x 8 rows
  float run = 0.f;
  int cur = -1;
#pragma unroll
  for (int j = 0; j < 8; ++j) {
    int r = grp * 8 + j;
    int gg = sbatch[r];
    if (gg != cur) {
      if (cur >= 0) atomicAdd(&out[(size_t)cur * 128 + f], run);
      run = 0.f; cur = gg;
    }
    if (gg >= 0) run += bf2f(smc[r * CP + f]);
  }
  if (cur >= 0) atomicAdd(&out[(size_t)cur * 128 + f], run);
}

// divide pooled sums by segment counts
__global__ void k_finalize(float* __restrict__ out, const int* __restrict__ gstart, int G) {
  int idx = blockIdx.x * blockDim.x + threadIdx.x;
  if (idx >= G * 128) return;
  int g = idx >> 7;
  float cnt = (float)(gstart[g + 1] - gstart[g]);
  out[idx] = out[idx] / fmaxf(cnt, 1.f);
}

extern "C" void kernel_launch(void* const* d_in, const int* in_sizes, int n_in,
                              void* d_out, int out_size, void* d_ws, size_t ws_size,
                              hipStream_t stream) {
  const float* x  = (const float*)d_in[0];
  const int* ei   = (const int*)d_in[1];
  const int* batch = (const int*)d_in[2];
  const float* W1 = (const float*)d_in[3];
  const float* b1 = (const float*)d_in[4];
  const float* W2 = (const float*)d_in[5];
  const float* b2 = (const float*)d_in[6];
  const float* W3 = (const float*)d_in[7];
  const float* b3 = (const float*)d_in[8];
  float* out = (float*)d_out;
  int N = in_sizes[2];
  int E = in_sizes[1] / 2;
  int G = out_size / HD;
  const int* src = ei;
  const int* dst = ei + E;

  size_t off = 0;
  char* ws = (char*)d_ws;
  auto alloc = [&](size_t bytes) -> void* {
    void* p = ws + off;
    off += (bytes + 255) & ~(size_t)255;
    return p;
  };
  int nb1024 = (N + 1023) / 1024;
  int*   deg     = (int*)alloc((size_t)N * 4);
  int*   scanbuf = (int*)alloc((size_t)nb1024 * 4);   // contiguous after deg -> one memset
  float* dinv    = (float*)alloc((size_t)N * 4);
  int*   rowptr  = (int*)alloc((size_t)(N + 1) * 4);
  int*   eord    = (int*)alloc((size_t)E * 4);
  unsigned int* col = (unsigned int*)alloc((size_t)E * 4);
  int*   gstart  = (int*)alloc((size_t)(G + 1) * 4);
  unsigned short* xb = (unsigned short*)alloc((size_t)N * 32 * 2);
  unsigned short* h1 = (unsigned short*)alloc((size_t)N * HD * 2);
  unsigned short* h2 = (unsigned short*)alloc((size_t)N * HD * 2);
  unsigned short* W1F = (unsigned short*)alloc(4096 * 2);
  unsigned short* W2F = (unsigned short*)alloc(16384 * 2);
  unsigned short* W3F = (unsigned short*)alloc(16384 * 2);
  (void)ws_size; (void)n_in;

  size_t zbytes = (size_t)((char*)dinv - (char*)deg);  // deg + scanbuf region
  hipMemsetAsync(deg, 0, zbytes, stream);
  k_degree<<<(E + 255) / 256, 256, 0, stream>>>(dst, deg, eord, E);
  k_scan<<<nb1024, 256, 0, stream>>>(deg, scanbuf, rowptr, dinv, N);

  int SB = (E + 255) / 256;
  int XB = (N * 32 + 255) / 256;
  int WB = 144;
  int BB = (N + 255) / 256;
  int ZB = (G * 32 + 255) / 256;
  k_prep<<<SB + XB + WB + BB + ZB, 256, 0, stream>>>(src, dst, rowptr, eord, col, E,
                                                     x, dinv, xb, N,
                                                     W1, W2, W3, W1F, W2F, W3F,
                                                     batch, gstart, G, out,
                                                     SB, XB, WB, BB);

  int fb = (N + 15) / 16;
  k_fused<32><<<fb, 256, 0, stream>>>(xb, W1F, b1, rowptr, col, dinv, h1, N);
  k_fused<128><<<fb, 256, 0, stream>>>(h1, W2F, b2, rowptr, col, dinv, h2, N);
  k_fused_pool<<<fb, 256, 0, stream>>>(h2, W3F, b3, rowptr, col, dinv, batch, out, N);
  k_finalize<<<(G * 128 + 255) / 256, 256, 0, stream>>>(out, gstart, G);
}

// Round 11
// 278.584 us; speedup vs baseline: 1.2649x; 1.2649x over previous
//
#include <hip/hip_runtime.h>

// 3-layer GCN + mean pool. MFMA GEMM / fp32 accumulate / bf16 interchange.
// R23 (resubmit; R10 bench was an infra acquisition failure, same mode as
// R7 which ran fine on identical resubmit).
// global_load_lds staging (1 wave-inst per KB) + bf16 add-reduce.
// Model from R14-R22: ~250 SIMD-cy/edge invariant to K, bytes, MLP,
// randomness, block size -> per-edge INSTRUCTION cost is the wall:
// R18 staging ~32 inst/edge + reduce ~23. Fix:
//  - stage via __builtin_amdgcn_global_load_lds width=16: per-lane global
//    addr (row from LDS-cached col chunk), linear LDS dest -> ~1.5
//    inst/edge. Compiler never auto-emits this.
//  - interchange = pre-scaled bf16 rows (R14-verified): reduce is pure
//    sum (extract+add, no dequant/scale) ~21 inst/edge.
//  - MFMA/deposit/C-store/pool/prep verbatim from passing R14/R18 code.

#define DIN 30
#define HD  128

typedef __attribute__((ext_vector_type(8))) short v8s;
typedef __attribute__((ext_vector_type(4))) float v4f;

static __device__ __forceinline__ unsigned short f2bf(float f) {
  unsigned int u = __float_as_uint(f);
  u += 0x7fffu + ((u >> 16) & 1u);   // RNE
  return (unsigned short)(u >> 16);
}
static __device__ __forceinline__ float bf2f(unsigned short s) {
  return __uint_as_float(((unsigned int)s) << 16);
}
static __device__ __forceinline__ float bflo(unsigned int u) {
  return __uint_as_float(u << 16);
}
static __device__ __forceinline__ float bfhi(unsigned int u) {
  return __uint_as_float(u & 0xffff0000u);
}

// async global->LDS, 16B per lane; LDS dest is wave-uniform base + lane*16
static __device__ __forceinline__ void gload_lds16(const void* g, void* l) {
  __builtin_amdgcn_global_load_lds(
      (const __attribute__((address_space(1))) void*)g,
      (__attribute__((address_space(3))) void*)l, 16, 0, 0);
}

// sum 8 bf16 (uint4) into a0..a7
#define ADD8(v)                          \
  {                                      \
    a0 += bflo((v).x); a1 += bfhi((v).x); \
    a2 += bflo((v).y); a3 += bfhi((v).y); \
    a4 += bflo((v).z); a5 += bfhi((v).z); \
    a6 += bflo((v).w); a7 += bfhi((v).w); \
  }

// ---------------- preprocessing ----------------
__global__ void k_degree(const int* __restrict__ dst, int* __restrict__ deg,
                         int* __restrict__ eord, int E) {
  int e = blockIdx.x * blockDim.x + threadIdx.x;
  if (e < E) eord[e] = atomicAdd(&deg[dst[e]], 1);
}

// single-dispatch exclusive scan (decoupled lookback, flag bit 31) + dinv.
__global__ void k_scan(const int* __restrict__ deg, int* __restrict__ scanbuf,
                       int* __restrict__ rowptr, float* __restrict__ dinv, int N) {
  __shared__ int s[256];
  __shared__ int sbase;
  int bid = blockIdx.x, tid = threadIdx.x;
  int base = bid * 1024 + tid * 4;
  int v[4]; int t = 0;
#pragma unroll
  for (int j = 0; j < 4; ++j) { int idx = base + j; v[j] = (idx < N) ? deg[idx] : 0; t += v[j]; }
  s[tid] = t; __syncthreads();
  for (int d = 1; d < 256; d <<= 1) {
    int u = (tid >= d) ? s[tid - d] : 0;
    __syncthreads();
    s[tid] += u;
    __syncthreads();
  }
  int myexcl = s[tid] - t;
  int blocktotal = s[255];
  if (tid == 0) atomicExch(&scanbuf[bid], blocktotal | 0x80000000);

  int pre = 0;
  for (int p = tid; p < bid; p += 256) {
    int val;
    do { val = atomicAdd(&scanbuf[p], 0); } while (!(val & 0x80000000));
    pre += val & 0x7fffffff;
  }
  __syncthreads();
  s[tid] = pre; __syncthreads();
  for (int d = 128; d > 0; d >>= 1) { if (tid < d) s[tid] += s[tid + d]; __syncthreads(); }
  if (tid == 0) sbase = s[0];
  __syncthreads();

  int run = sbase + myexcl;
#pragma unroll
  for (int j = 0; j < 4; ++j) {
    int idx = base + j;
    if (idx < N) {
      rowptr[idx] = run;
      dinv[idx] = rsqrtf((float)(1 + v[j]));
    }
    run += v[j];
    if (idx == N - 1) rowptr[N] = run;
  }
}

// fragment-major weight pack helper
static __device__ __forceinline__ void wtf_one(const float* __restrict__ W,
                                               unsigned short* __restrict__ WTF,
                                               int idx, int Kreal, int KK) {
  int j = idx & 7;
  int c = idx >> 3;
  int l15 = c & 15;
  int quad = (c >> 4) & 3;
  int kk = (c >> 6) % KK;
  int t = c / (64 * KK);
  int k = kk * 32 + quad * 8 + j;
  int n = t * 16 + l15;
  WTF[idx] = (k < Kreal) ? f2bf(W[k * 128 + n]) : (unsigned short)0;
}

// merged prep: atomic-free CSR scatter | xcast | wtf | bounds | out-zero
__global__ void k_prep(const int* __restrict__ src, const int* __restrict__ dst,
                       const int* __restrict__ rowptr, const int* __restrict__ eord,
                       int* __restrict__ col, int E,
                       const float* __restrict__ x, const float* __restrict__ dinv,
                       unsigned short* __restrict__ xb, int N,
                       const float* __restrict__ W1, const float* __restrict__ W2,
                       const float* __restrict__ W3,
                       unsigned short* __restrict__ W1F, unsigned short* __restrict__ W2F,
                       unsigned short* __restrict__ W3F,
                       const int* __restrict__ batch, int* __restrict__ gstart, int G,
                       float* __restrict__ out,
                       int SB, int XB, int WB, int BB) {
  int blk = blockIdx.x;
  if (blk < SB) {
    int e = blk * 256 + threadIdx.x;
    if (e < E) col[rowptr[dst[e]] + eord[e]] = src[e];
  } else if (blk < SB + XB) {
    int idx = (blk - SB) * 256 + threadIdx.x;
    if (idx < N * 32) {
      int n = idx >> 5, f = idx & 31;
      float v = (f < DIN) ? x[(size_t)n * DIN + f] * dinv[n] : 0.f;
      xb[idx] = f2bf(v);
    }
  } else if (blk < SB + XB + WB) {
    int idx = (blk - SB - XB) * 256 + threadIdx.x;
    if (idx < 4096) wtf_one(W1, W1F, idx, DIN, 1);
    else if (idx < 20480) wtf_one(W2, W2F, idx - 4096, 128, 4);
    else if (idx < 36864) wtf_one(W3, W3F, idx - 20480, 128, 4);
  } else if (blk < SB + XB + WB + BB) {
    int i = (blk - SB - XB - WB) * 256 + threadIdx.x;
    if (i >= N) return;
    int b = batch[i];
    int prev = (i == 0) ? -1 : batch[i - 1];
    for (int g = prev + 1; g <= b; ++g) gstart[g] = i;
    if (i == N - 1)
      for (int g = b + 1; g <= G; ++g) gstart[g] = N;
  } else {
    int idx = (blk - SB - XB - WB - BB) * 256 + threadIdx.x;
    if (idx < G * 32)
      ((float4*)out)[idx] = make_float4(0.f, 0.f, 0.f, 0.f);
  }
}

// ---------------- fused aggregate + MFMA GEMM (layers 1,2) ----------------
// 1024 threads / 64 nodes. hin: pre-scaled bf16 rows (K feats).
// Stage: global_load_lds 16B/lane into linear stg; reduce: register sum.
template <int K>
__global__ __launch_bounds__(1024, 8) void k_fused(const unsigned short* __restrict__ hin,
                                                   const unsigned short* __restrict__ WTF,
                                                   const float* __restrict__ b,
                                                   const int* __restrict__ rowptr,
                                                   const int* __restrict__ col,
                                                   const float* __restrict__ dinv,
                                                   unsigned short* __restrict__ C, int N) {
  constexpr int KK = K / 32;
  constexpr int KP = (K == 128) ? 136 : 40;
  constexpr int CP = 132;
  constexpr int SMSZ = (64 * KP > 64 * CP) ? 64 * KP : 64 * CP;
  constexpr int CH = (K == 128) ? 128 : 256;    // edges per staging chunk
  constexpr int RB = K * 2;                     // row bytes
  __shared__ __align__(16) unsigned short sm[SMSZ];
  __shared__ __align__(16) unsigned char stg[CH * RB];
  __shared__ int smcol[CH];

  int tid = threadIdx.x;
  int l16 = tid & 15;
  int g = tid >> 4;                 // group g owns node row0+g
  int lane = tid & 63, wv = tid >> 6, quad = lane >> 4, l15 = lane & 15;
  int row0 = blockIdx.x * 64;
  int node = row0 + g;
  int rend = row0 + 64; if (rend > N) rend = N;

  // ---- phase 1a: self term (pre-scaled row) + ranges ----
  float a0 = 0.f, a1 = 0.f, a2 = 0.f, a3 = 0.f, a4 = 0.f, a5 = 0.f, a6 = 0.f, a7 = 0.f;
  int e0 = 0, e1 = 0; float di = 0.f;
  if (node < N) {
    e0 = rowptr[node]; e1 = rowptr[node + 1]; di = dinv[node];
    if constexpr (K == 32) {
      unsigned int u = ((const unsigned int*)hin)[(size_t)node * 16 + l16];
      a0 = bflo(u); a1 = bfhi(u);
    } else {
      uint4 u = ((const uint4*)hin)[(size_t)node * 16 + l16];
      ADD8(u);
    }
  }
  int eb = rowptr[row0];
  int ee = rowptr[rend];

  // ---- phase 1b: chunked async stage + register sum ----
  for (int c0 = eb; c0 < ee; c0 += CH) {
    if (tid < CH) {
      int e = c0 + tid;
      smcol[tid] = (e < ee) ? col[e] : 0;      // clamp: safe row 0
    }
    __syncthreads();
    if constexpr (K == 128) {
      // wave covers 8 slots (2 issues x 4 slots x 256B)
#pragma unroll
      for (int q = 0; q < 2; ++q) {
        int slb = wv * 8 + q * 4;
        int row = smcol[slb + (lane >> 4)];
        const unsigned short* gp = hin + (size_t)row * 128 + (lane & 15) * 8;
        gload_lds16(gp, &stg[slb * 256]);
      }
    } else {
      // wave covers 16 slots (1 issue x 16 slots x 64B)
      int slb = wv * 16;
      int row = smcol[slb + (lane >> 2)];
      const unsigned short* gp = hin + (size_t)row * 32 + (lane & 3) * 8;
      gload_lds16(gp, &stg[slb * 64]);
    }
    __syncthreads();                            // drain loads
    int lo = (e0 > c0) ? e0 : c0;
    int hi = (e1 < c0 + CH) ? e1 : (c0 + CH);
    int e2 = lo;
    for (; e2 + 2 <= hi; e2 += 2) {
      int i0 = e2 - c0, i1 = i0 + 1;
      if constexpr (K == 32) {
        unsigned int w0 = *(const unsigned int*)&stg[i0 * 64 + l16 * 4];
        unsigned int w1 = *(const unsigned int*)&stg[i1 * 64 + l16 * 4];
        a0 += bflo(w0); a1 += bfhi(w0);
        a0 += bflo(w1); a1 += bfhi(w1);
      } else {
        uint4 w0 = *(const uint4*)&stg[i0 * 256 + l16 * 16];
        uint4 w1 = *(const uint4*)&stg[i1 * 256 + l16 * 16];
        ADD8(w0);
        ADD8(w1);
      }
    }
    if (e2 < hi) {
      int i0 = e2 - c0;
      if constexpr (K == 32) {
        unsigned int w0 = *(const unsigned int*)&stg[i0 * 64 + l16 * 4];
        a0 += bflo(w0); a1 += bfhi(w0);
      } else {
        uint4 w0 = *(const uint4*)&stg[i0 * 256 + l16 * 16];
        ADD8(w0);
      }
    }
    __syncthreads();                            // protect stg/smcol reuse
  }

  // ---- phase 1c: deposit normalized bf16 A-tile ----
  if constexpr (K == 32) {
    *(unsigned int*)&sm[g * KP + l16 * 2] =
        (unsigned int)f2bf(a0 * di) | ((unsigned int)f2bf(a1 * di) << 16);
  } else {
    uint4 o;
    o.x = (unsigned int)f2bf(a0 * di) | ((unsigned int)f2bf(a1 * di) << 16);
    o.y = (unsigned int)f2bf(a2 * di) | ((unsigned int)f2bf(a3 * di) << 16);
    o.z = (unsigned int)f2bf(a4 * di) | ((unsigned int)f2bf(a5 * di) << 16);
    o.w = (unsigned int)f2bf(a6 * di) | ((unsigned int)f2bf(a7 * di) << 16);
    *(uint4*)&sm[g * KP + l16 * 8] = o;
  }
  __syncthreads();

  // ---- phase 2: A-frags from LDS; 16 waves = 4 row-tiles x 4 t-pairs ----
  int rt = wv & 3, tp = wv >> 2;
  v8s af[KK];
#pragma unroll
  for (int kk = 0; kk < KK; ++kk)
    af[kk] = *(const v8s*)&sm[(rt * 16 + l15) * KP + kk * 32 + quad * 8];
  __syncthreads();

  // hoisted next-layer pre-scale: dinv for this lane's 4 output rows
  int crow0 = row0 + rt * 16 + quad * 4;
  float dr[4];
  if (crow0 + 3 < N) {
    float4 d4 = *(const float4*)&dinv[crow0];
    dr[0] = d4.x; dr[1] = d4.y; dr[2] = d4.z; dr[3] = d4.w;
  } else {
#pragma unroll
    for (int i = 0; i < 4; ++i) dr[i] = (crow0 + i < N) ? dinv[crow0 + i] : 0.f;
  }

#pragma unroll
  for (int tt = 0; tt < 2; ++tt) {
    int t = tp * 2 + tt;
    v4f acc = {0.f, 0.f, 0.f, 0.f};
#pragma unroll
    for (int kk = 0; kk < KK; ++kk) {
      v8s bf = *(const v8s*)(WTF + (size_t)(((t * KK + kk) * 4 + quad) * 16 + l15) * 8);
      acc = __builtin_amdgcn_mfma_f32_16x16x32_bf16(af[kk], bf, acc, 0, 0, 0);
    }
    float bias = b[t * 16 + l15];
#pragma unroll
    for (int i = 0; i < 4; ++i) {
      float o = fmaxf(acc[i] + bias, 0.f) * dr[i];
      sm[(rt * 16 + quad * 4 + i) * CP + t * 16 + l15] = f2bf(o);
    }
  }
  __syncthreads();

  // ---- phase 3: coalesced C store ----
#pragma unroll
  for (int j = 0; j < 2; ++j) {
    int linear = j * 1024 + tid;
    int r = linear >> 5, ch = linear & 31;
    uint2 v = *(const uint2*)&sm[r * CP + ch * 4];
    int row = row0 + r;
    if (row < N) ((uint2*)C)[(size_t)row * 32 + ch] = v;
  }
}

// ---------------- layer 3: fused aggregate + GEMM + pool-atomics ----------------
__global__ __launch_bounds__(1024, 8) void k_fused_pool(const unsigned short* __restrict__ hin,
                                                        const unsigned short* __restrict__ WTF,
                                                        const float* __restrict__ b,
                                                        const int* __restrict__ rowptr,
                                                        const int* __restrict__ col,
                                                        const float* __restrict__ dinv,
                                                        const int* __restrict__ batch,
                                                        float* __restrict__ out, int N) {
  constexpr int KK = 4, KP = 136, CP = 132;
  constexpr int SMSZ = 64 * KP;
  constexpr int CH = 128;
  __shared__ __align__(16) unsigned short sm[SMSZ];
  __shared__ __align__(16) unsigned char stg[CH * 256];
  __shared__ int smcol[CH];
  __shared__ int sbatch[64];

  int tid = threadIdx.x;
  int l16 = tid & 15;
  int g = tid >> 4;
  int lane = tid & 63, wv = tid >> 6, quad = lane >> 4, l15 = lane & 15;
  int row0 = blockIdx.x * 64;
  int node = row0 + g;
  int rend = row0 + 64; if (rend > N) rend = N;

  if (tid < 64) sbatch[tid] = (row0 + tid < N) ? batch[row0 + tid] : -1;

  // ---- phase 1a ----
  float a0 = 0.f, a1 = 0.f, a2 = 0.f, a3 = 0.f, a4 = 0.f, a5 = 0.f, a6 = 0.f, a7 = 0.f;
  int e0 = 0, e1 = 0; float di = 0.f;
  if (node < N) {
    e0 = rowptr[node]; e1 = rowptr[node + 1]; di = dinv[node];
    uint4 u = ((const uint4*)hin)[(size_t)node * 16 + l16];
    ADD8(u);
  }
  int eb = rowptr[row0];
  int ee = rowptr[rend];

  // ---- phase 1b ----
  for (int c0 = eb; c0 < ee; c0 += CH) {
    if (tid < CH) {
      int e = c0 + tid;
      smcol[tid] = (e < ee) ? col[e] : 0;
    }
    __syncthreads();
#pragma unroll
    for (int q = 0; q < 2; ++q) {
      int slb = wv * 8 + q * 4;
      int row = smcol[slb + (lane >> 4)];
      const unsigned short* gp = hin + (size_t)row * 128 + (lane & 15) * 8;
      gload_lds16(gp, &stg[slb * 256]);
    }
    __syncthreads();
    int lo = (e0 > c0) ? e0 : c0;
    int hi = (e1 < c0 + CH) ? e1 : (c0 + CH);
    int e2 = lo;
    for (; e2 + 2 <= hi; e2 += 2) {
      int i0 = e2 - c0, i1 = i0 + 1;
      uint4 w0 = *(const uint4*)&stg[i0 * 256 + l16 * 16];
      uint4 w1 = *(const uint4*)&stg[i1 * 256 + l16 * 16];
      ADD8(w0);
      ADD8(w1);
    }
    if (e2 < hi) {
      int i0 = e2 - c0;
      uint4 w0 = *(const uint4*)&stg[i0 * 256 + l16 * 16];
      ADD8(w0);
    }
    __syncthreads();
  }

  // ---- phase 1c: deposit normalized bf16 A-tile ----
  {
    uint4 o;
    o.x = (unsigned int)f2bf(a0 * di) | ((unsigned int)f2bf(a1 * di) << 16);
    o.y = (unsigned int)f2bf(a2 * di) | ((unsigned int)f2bf(a3 * di) << 16);
    o.z = (unsigned int)f2bf(a4 * di) | ((unsigned int)f2bf(a5 * di) << 16);
    o.w = (unsigned int)f2bf(a6 * di) | ((unsigned int)f2bf(a7 * di) << 16);
    *(uint4*)&sm[g * KP + l16 * 8] = o;
  }
  __syncthreads();

  // ---- phase 2 (no epilogue scaling: pool needs raw h3) ----
  int rt = wv & 3, tp = wv >> 2;
  v8s af[KK];
#pragma unroll
  for (int kk = 0; kk < KK; ++kk)
    af[kk] = *(const v8s*)&sm[(rt * 16 + l15) * KP + kk * 32 + quad * 8];
  __syncthreads();

#pragma unroll
  for (int tt = 0; tt < 2; ++tt) {
    int t = tp * 2 + tt;
    v4f acc = {0.f, 0.f, 0.f, 0.f};
#pragma unroll
    for (int kk = 0; kk < KK; ++kk) {
      v8s bf = *(const v8s*)(WTF + (size_t)(((t * KK + kk) * 4 + quad) * 16 + l15) * 8);
      acc = __builtin_amdgcn_mfma_f32_16x16x32_bf16(af[kk], bf, acc, 0, 0, 0);
    }
    float bias = b[t * 16 + l15];
#pragma unroll
    for (int i = 0; i < 4; ++i) {
      float o = fmaxf(acc[i] + bias, 0.f);
      sm[(rt * 16 + quad * 4 + i) * CP + t * 16 + l15] = f2bf(o);
    }
  }
  __syncthreads();

  // ---- phase 3: segment-sum the 64 sorted rows, atomicAdd partials ----
  int f = tid & 127;
  int grp = tid >> 7;
  float run = 0.f;
  int cur = -1;
#pragma unroll
  for (int j = 0; j < 8; ++j) {
    int r = grp * 8 + j;
    int gg = sbatch[r];
    if (gg != cur) {
      if (cur >= 0) atomicAdd(&out[(size_t)cur * 128 + f], run);
      run = 0.f; cur = gg;
    }
    if (gg >= 0) run += bf2f(sm[r * CP + f]);
  }
  if (cur >= 0) atomicAdd(&out[(size_t)cur * 128 + f], run);
}

// divide pooled sums by segment counts
__global__ void k_finalize(float* __restrict__ out, const int* __restrict__ gstart, int G) {
  int idx = blockIdx.x * blockDim.x + threadIdx.x;
  if (idx >= G * 128) return;
  int g = idx >> 7;
  float cnt = (float)(gstart[g + 1] - gstart[g]);
  out[idx] = out[idx] / fmaxf(cnt, 1.f);
}

extern "C" void kernel_launch(void* const* d_in, const int* in_sizes, int n_in,
                              void* d_out, int out_size, void* d_ws, size_t ws_size,
                              hipStream_t stream) {
  const float* x  = (const float*)d_in[0];
  const int* ei   = (const int*)d_in[1];
  const int* batch = (const int*)d_in[2];
  const float* W1 = (const float*)d_in[3];
  const float* b1 = (const float*)d_in[4];
  const float* W2 = (const float*)d_in[5];
  const float* b2 = (const float*)d_in[6];
  const float* W3 = (const float*)d_in[7];
  const float* b3 = (const float*)d_in[8];
  float* out = (float*)d_out;
  int N = in_sizes[2];
  int E = in_sizes[1] / 2;
  int G = out_size / HD;
  const int* src = ei;
  const int* dst = ei + E;

  size_t off = 0;
  char* ws = (char*)d_ws;
  auto alloc = [&](size_t bytes) -> void* {
    void* p = ws + off;
    off += (bytes + 255) & ~(size_t)255;
    return p;
  };
  int nb1024 = (N + 1023) / 1024;
  int*   deg     = (int*)alloc((size_t)N * 4);
  int*   scanbuf = (int*)alloc((size_t)nb1024 * 4);   // contiguous after deg -> one memset
  float* dinv    = (float*)alloc((size_t)N * 4);
  int*   rowptr  = (int*)alloc((size_t)(N + 1) * 4);
  int*   eord    = (int*)alloc((size_t)E * 4);
  int*   col     = (int*)alloc((size_t)E * 4);
  int*   gstart  = (int*)alloc((size_t)(G + 1) * 4);
  unsigned short* xb = (unsigned short*)alloc((size_t)N * 32 * 2);
  unsigned short* hA = (unsigned short*)alloc((size_t)N * HD * 2);
  unsigned short* hB = (unsigned short*)alloc((size_t)N * HD * 2);
  unsigned short* W1F = (unsigned short*)alloc(4096 * 2);
  unsigned short* W2F = (unsigned short*)alloc(16384 * 2);
  unsigned short* W3F = (unsigned short*)alloc(16384 * 2);
  (void)ws_size; (void)n_in;

  size_t zbytes = (size_t)((char*)dinv - (char*)deg);  // deg + scanbuf region
  hipMemsetAsync(deg, 0, zbytes, stream);
  k_degree<<<(E + 255) / 256, 256, 0, stream>>>(dst, deg, eord, E);
  k_scan<<<nb1024, 256, 0, stream>>>(deg, scanbuf, rowptr, dinv, N);

  int SB = (E + 255) / 256;
  int XB = (N * 32 + 255) / 256;
  int WB = 144;
  int BB = (N + 255) / 256;
  int ZB = (G * 32 + 255) / 256;   // out zero, float4/thread
  k_prep<<<SB + XB + WB + BB + ZB, 256, 0, stream>>>(src, dst, rowptr, eord, col, E,
                                                     x, dinv, xb, N,
                                                     W1, W2, W3, W1F, W2F, W3F,
                                                     batch, gstart, G, out,
                                                     SB, XB, WB, BB);

  int fusedBlocks = (N + 63) / 64;
  k_fused<32><<<fusedBlocks, 1024, 0, stream>>>(xb, W1F, b1, rowptr, col, dinv, hA, N);
  k_fused<128><<<fusedBlocks, 1024, 0, stream>>>(hA, W2F, b2, rowptr, col, dinv, hB, N);
  k_fused_pool<<<fusedBlocks, 1024, 0, stream>>>(hB, W3F, b3, rowptr, col, dinv, batch, out, N);
  k_finalize<<<(G * 128 + 255) / 256, 256, 0, stream>>>(out, gstart, G);
}

// Round 12
// 256.474 us; speedup vs baseline: 1.3739x; 1.0862x over previous
//
#include <hip/hip_runtime.h>

// 3-layer GCN + mean pool. MFMA GEMM / fp32 accumulate / bf16 interchange.
// R24: R23 staging (global_load_lds) at 512-thr/8-wave/32-node blocks.
// R23 result: staging-instruction collapse (32->1.5/edge) = null on layer
// time (61.6us, == R14's 62.5). Remaining untested axis: block-level
// overlap. 1024-thr blocks are wave-capped at 2 resident/CU -> each
// chunk's vmcnt(0) drain has 1 peer to hide behind. This round:
//  - 512 threads / 32 nodes / CH=96 -> LDS 33.7KB -> 4 blocks/CU
//  - typical block (avg 96 edges) stages in ONE chunk
//  - all staging/reduce/MFMA/epilogue logic identical to R23, re-indexed
// If layers stay ~62us, every axis is exonerated -> declare the wall.

#define DIN 30
#define HD  128

typedef __attribute__((ext_vector_type(8))) short v8s;
typedef __attribute__((ext_vector_type(4))) float v4f;

static __device__ __forceinline__ unsigned short f2bf(float f) {
  unsigned int u = __float_as_uint(f);
  u += 0x7fffu + ((u >> 16) & 1u);   // RNE
  return (unsigned short)(u >> 16);
}
static __device__ __forceinline__ float bf2f(unsigned short s) {
  return __uint_as_float(((unsigned int)s) << 16);
}
static __device__ __forceinline__ float bflo(unsigned int u) {
  return __uint_as_float(u << 16);
}
static __device__ __forceinline__ float bfhi(unsigned int u) {
  return __uint_as_float(u & 0xffff0000u);
}

// async global->LDS, 16B per lane; LDS dest is wave-uniform base + lane*16
static __device__ __forceinline__ void gload_lds16(const void* g, void* l) {
  __builtin_amdgcn_global_load_lds(
      (const __attribute__((address_space(1))) void*)g,
      (__attribute__((address_space(3))) void*)l, 16, 0, 0);
}

// sum 8 bf16 (uint4) into a0..a7
#define ADD8(v)                          \
  {                                      \
    a0 += bflo((v).x); a1 += bfhi((v).x); \
    a2 += bflo((v).y); a3 += bfhi((v).y); \
    a4 += bflo((v).z); a5 += bfhi((v).z); \
    a6 += bflo((v).w); a7 += bfhi((v).w); \
  }

// ---------------- preprocessing ----------------
__global__ void k_degree(const int* __restrict__ dst, int* __restrict__ deg,
                         int* __restrict__ eord, int E) {
  int e = blockIdx.x * blockDim.x + threadIdx.x;
  if (e < E) eord[e] = atomicAdd(&deg[dst[e]], 1);
}

// single-dispatch exclusive scan (decoupled lookback, flag bit 31) + dinv.
__global__ void k_scan(const int* __restrict__ deg, int* __restrict__ scanbuf,
                       int* __restrict__ rowptr, float* __restrict__ dinv, int N) {
  __shared__ int s[256];
  __shared__ int sbase;
  int bid = blockIdx.x, tid = threadIdx.x;
  int base = bid * 1024 + tid * 4;
  int v[4]; int t = 0;
#pragma unroll
  for (int j = 0; j < 4; ++j) { int idx = base + j; v[j] = (idx < N) ? deg[idx] : 0; t += v[j]; }
  s[tid] = t; __syncthreads();
  for (int d = 1; d < 256; d <<= 1) {
    int u = (tid >= d) ? s[tid - d] : 0;
    __syncthreads();
    s[tid] += u;
    __syncthreads();
  }
  int myexcl = s[tid] - t;
  int blocktotal = s[255];
  if (tid == 0) atomicExch(&scanbuf[bid], blocktotal | 0x80000000);

  int pre = 0;
  for (int p = tid; p < bid; p += 256) {
    int val;
    do { val = atomicAdd(&scanbuf[p], 0); } while (!(val & 0x80000000));
    pre += val & 0x7fffffff;
  }
  __syncthreads();
  s[tid] = pre; __syncthreads();
  for (int d = 128; d > 0; d >>= 1) { if (tid < d) s[tid] += s[tid + d]; __syncthreads(); }
  if (tid == 0) sbase = s[0];
  __syncthreads();

  int run = sbase + myexcl;
#pragma unroll
  for (int j = 0; j < 4; ++j) {
    int idx = base + j;
    if (idx < N) {
      rowptr[idx] = run;
      dinv[idx] = rsqrtf((float)(1 + v[j]));
    }
    run += v[j];
    if (idx == N - 1) rowptr[N] = run;
  }
}

// fragment-major weight pack helper
static __device__ __forceinline__ void wtf_one(const float* __restrict__ W,
                                               unsigned short* __restrict__ WTF,
                                               int idx, int Kreal, int KK) {
  int j = idx & 7;
  int c = idx >> 3;
  int l15 = c & 15;
  int quad = (c >> 4) & 3;
  int kk = (c >> 6) % KK;
  int t = c / (64 * KK);
  int k = kk * 32 + quad * 8 + j;
  int n = t * 16 + l15;
  WTF[idx] = (k < Kreal) ? f2bf(W[k * 128 + n]) : (unsigned short)0;
}

// merged prep: atomic-free CSR scatter | xcast | wtf | bounds | out-zero
__global__ void k_prep(const int* __restrict__ src, const int* __restrict__ dst,
                       const int* __restrict__ rowptr, const int* __restrict__ eord,
                       int* __restrict__ col, int E,
                       const float* __restrict__ x, const float* __restrict__ dinv,
                       unsigned short* __restrict__ xb, int N,
                       const float* __restrict__ W1, const float* __restrict__ W2,
                       const float* __restrict__ W3,
                       unsigned short* __restrict__ W1F, unsigned short* __restrict__ W2F,
                       unsigned short* __restrict__ W3F,
                       const int* __restrict__ batch, int* __restrict__ gstart, int G,
                       float* __restrict__ out,
                       int SB, int XB, int WB, int BB) {
  int blk = blockIdx.x;
  if (blk < SB) {
    int e = blk * 256 + threadIdx.x;
    if (e < E) col[rowptr[dst[e]] + eord[e]] = src[e];
  } else if (blk < SB + XB) {
    int idx = (blk - SB) * 256 + threadIdx.x;
    if (idx < N * 32) {
      int n = idx >> 5, f = idx & 31;
      float v = (f < DIN) ? x[(size_t)n * DIN + f] * dinv[n] : 0.f;
      xb[idx] = f2bf(v);
    }
  } else if (blk < SB + XB + WB) {
    int idx = (blk - SB - XB) * 256 + threadIdx.x;
    if (idx < 4096) wtf_one(W1, W1F, idx, DIN, 1);
    else if (idx < 20480) wtf_one(W2, W2F, idx - 4096, 128, 4);
    else if (idx < 36864) wtf_one(W3, W3F, idx - 20480, 128, 4);
  } else if (blk < SB + XB + WB + BB) {
    int i = (blk - SB - XB - WB) * 256 + threadIdx.x;
    if (i >= N) return;
    int b = batch[i];
    int prev = (i == 0) ? -1 : batch[i - 1];
    for (int g = prev + 1; g <= b; ++g) gstart[g] = i;
    if (i == N - 1)
      for (int g = b + 1; g <= G; ++g) gstart[g] = N;
  } else {
    int idx = (blk - SB - XB - WB - BB) * 256 + threadIdx.x;
    if (idx < G * 32)
      ((float4*)out)[idx] = make_float4(0.f, 0.f, 0.f, 0.f);
  }
}

// ---------------- fused aggregate + MFMA GEMM (layers 1,2) ----------------
// 512 threads / 32 nodes / 8 waves. hin: pre-scaled bf16 rows (K feats).
template <int K>
__global__ __launch_bounds__(512, 8) void k_fused(const unsigned short* __restrict__ hin,
                                                  const unsigned short* __restrict__ WTF,
                                                  const float* __restrict__ b,
                                                  const int* __restrict__ rowptr,
                                                  const int* __restrict__ col,
                                                  const float* __restrict__ dinv,
                                                  unsigned short* __restrict__ C, int N) {
  constexpr int KK = K / 32;
  constexpr int KP = (K == 128) ? 136 : 40;
  constexpr int CP = 132;
  constexpr int SMSZ = (32 * KP > 32 * CP) ? 32 * KP : 32 * CP;
  constexpr int CH = (K == 128) ? 96 : 128;     // edges per staging chunk
  constexpr int RB = K * 2;                     // row bytes
  __shared__ __align__(16) unsigned short sm[SMSZ];
  __shared__ __align__(16) unsigned char stg[CH * RB];
  __shared__ int smcol[CH];

  int tid = threadIdx.x;
  int l16 = tid & 15;
  int g = tid >> 4;                 // 32 groups of 16 lanes
  int lane = tid & 63, wv = tid >> 6, quad = lane >> 4, l15 = lane & 15;
  int row0 = blockIdx.x * 32;
  int node = row0 + g;
  int rend = row0 + 32; if (rend > N) rend = N;

  // ---- phase 1a: self term + ranges ----
  float a0 = 0.f, a1 = 0.f, a2 = 0.f, a3 = 0.f, a4 = 0.f, a5 = 0.f, a6 = 0.f, a7 = 0.f;
  int e0 = 0, e1 = 0; float di = 0.f;
  if (node < N) {
    e0 = rowptr[node]; e1 = rowptr[node + 1]; di = dinv[node];
    if constexpr (K == 32) {
      unsigned int u = ((const unsigned int*)hin)[(size_t)node * 16 + l16];
      a0 = bflo(u); a1 = bfhi(u);
    } else {
      uint4 u = ((const uint4*)hin)[(size_t)node * 16 + l16];
      ADD8(u);
    }
  }
  int eb = rowptr[row0];
  int ee = rowptr[rend];

  // ---- phase 1b: chunked async stage + register sum ----
  for (int c0 = eb; c0 < ee; c0 += CH) {
    if (tid < CH) {
      int e = c0 + tid;
      smcol[tid] = (e < ee) ? col[e] : 0;      // clamp: safe row 0
    }
    __syncthreads();
    if constexpr (K == 128) {
      // wave covers 12 slots (3 issues x 4 slots x 256B); 8 waves x 12 = 96
#pragma unroll
      for (int q = 0; q < 3; ++q) {
        int slb = wv * 12 + q * 4;
        int row = smcol[slb + (lane >> 4)];
        const unsigned short* gp = hin + (size_t)row * 128 + (lane & 15) * 8;
        gload_lds16(gp, &stg[slb * 256]);
      }
    } else {
      // wave covers 16 slots (1 issue x 16 slots x 64B); 8 x 16 = 128
      int slb = wv * 16;
      int row = smcol[slb + (lane >> 2)];
      const unsigned short* gp = hin + (size_t)row * 32 + (lane & 3) * 8;
      gload_lds16(gp, &stg[slb * 64]);
    }
    __syncthreads();                            // drain loads
    int lo = (e0 > c0) ? e0 : c0;
    int hi = (e1 < c0 + CH) ? e1 : (c0 + CH);
    int e2 = lo;
    for (; e2 + 2 <= hi; e2 += 2) {
      int i0 = e2 - c0, i1 = i0 + 1;
      if constexpr (K == 32) {
        unsigned int w0 = *(const unsigned int*)&stg[i0 * 64 + l16 * 4];
        unsigned int w1 = *(const unsigned int*)&stg[i1 * 64 + l16 * 4];
        a0 += bflo(w0); a1 += bfhi(w0);
        a0 += bflo(w1); a1 += bfhi(w1);
      } else {
        uint4 w0 = *(const uint4*)&stg[i0 * 256 + l16 * 16];
        uint4 w1 = *(const uint4*)&stg[i1 * 256 + l16 * 16];
        ADD8(w0);
        ADD8(w1);
      }
    }
    if (e2 < hi) {
      int i0 = e2 - c0;
      if constexpr (K == 32) {
        unsigned int w0 = *(const unsigned int*)&stg[i0 * 64 + l16 * 4];
        a0 += bflo(w0); a1 += bfhi(w0);
      } else {
        uint4 w0 = *(const uint4*)&stg[i0 * 256 + l16 * 16];
        ADD8(w0);
      }
    }
    __syncthreads();                            // protect stg/smcol reuse
  }

  // ---- phase 1c: deposit normalized bf16 A-tile ----
  if constexpr (K == 32) {
    *(unsigned int*)&sm[g * KP + l16 * 2] =
        (unsigned int)f2bf(a0 * di) | ((unsigned int)f2bf(a1 * di) << 16);
  } else {
    uint4 o;
    o.x = (unsigned int)f2bf(a0 * di) | ((unsigned int)f2bf(a1 * di) << 16);
    o.y = (unsigned int)f2bf(a2 * di) | ((unsigned int)f2bf(a3 * di) << 16);
    o.z = (unsigned int)f2bf(a4 * di) | ((unsigned int)f2bf(a5 * di) << 16);
    o.w = (unsigned int)f2bf(a6 * di) | ((unsigned int)f2bf(a7 * di) << 16);
    *(uint4*)&sm[g * KP + l16 * 8] = o;
  }
  __syncthreads();

  // ---- phase 2: A-frags from LDS; 8 waves = 2 row-tiles x 4 t-pairs ----
  int rt = wv & 1, tp = wv >> 1;
  v8s af[KK];
#pragma unroll
  for (int kk = 0; kk < KK; ++kk)
    af[kk] = *(const v8s*)&sm[(rt * 16 + l15) * KP + kk * 32 + quad * 8];
  __syncthreads();

  // hoisted next-layer pre-scale: dinv for this lane's 4 output rows
  int crow0 = row0 + rt * 16 + quad * 4;
  float dr[4];
  if (crow0 + 3 < N) {
    float4 d4 = *(const float4*)&dinv[crow0];
    dr[0] = d4.x; dr[1] = d4.y; dr[2] = d4.z; dr[3] = d4.w;
  } else {
#pragma unroll
    for (int i = 0; i < 4; ++i) dr[i] = (crow0 + i < N) ? dinv[crow0 + i] : 0.f;
  }

#pragma unroll
  for (int tt = 0; tt < 2; ++tt) {
    int t = tp * 2 + tt;
    v4f acc = {0.f, 0.f, 0.f, 0.f};
#pragma unroll
    for (int kk = 0; kk < KK; ++kk) {
      v8s bf = *(const v8s*)(WTF + (size_t)(((t * KK + kk) * 4 + quad) * 16 + l15) * 8);
      acc = __builtin_amdgcn_mfma_f32_16x16x32_bf16(af[kk], bf, acc, 0, 0, 0);
    }
    float bias = b[t * 16 + l15];
#pragma unroll
    for (int i = 0; i < 4; ++i) {
      float o = fmaxf(acc[i] + bias, 0.f) * dr[i];
      sm[(rt * 16 + quad * 4 + i) * CP + t * 16 + l15] = f2bf(o);
    }
  }
  __syncthreads();

  // ---- phase 3: coalesced C store (32 rows x 32 uint2 = 1024) ----
#pragma unroll
  for (int j = 0; j < 2; ++j) {
    int linear = j * 512 + tid;
    int r = linear >> 5, ch = linear & 31;
    uint2 v = *(const uint2*)&sm[r * CP + ch * 4];
    int row = row0 + r;
    if (row < N) ((uint2*)C)[(size_t)row * 32 + ch] = v;
  }
}

// ---------------- layer 3: fused aggregate + GEMM + pool-atomics ----------------
__global__ __launch_bounds__(512, 8) void k_fused_pool(const unsigned short* __restrict__ hin,
                                                       const unsigned short* __restrict__ WTF,
                                                       const float* __restrict__ b,
                                                       const int* __restrict__ rowptr,
                                                       const int* __restrict__ col,
                                                       const float* __restrict__ dinv,
                                                       const int* __restrict__ batch,
                                                       float* __restrict__ out, int N) {
  constexpr int KK = 4, KP = 136, CP = 132;
  constexpr int SMSZ = 32 * KP;
  constexpr int CH = 96;
  __shared__ __align__(16) unsigned short sm[SMSZ];
  __shared__ __align__(16) unsigned char stg[CH * 256];
  __shared__ int smcol[CH];
  __shared__ int sbatch[32];

  int tid = threadIdx.x;
  int l16 = tid & 15;
  int g = tid >> 4;
  int lane = tid & 63, wv = tid >> 6, quad = lane >> 4, l15 = lane & 15;
  int row0 = blockIdx.x * 32;
  int node = row0 + g;
  int rend = row0 + 32; if (rend > N) rend = N;

  if (tid < 32) sbatch[tid] = (row0 + tid < N) ? batch[row0 + tid] : -1;

  // ---- phase 1a ----
  float a0 = 0.f, a1 = 0.f, a2 = 0.f, a3 = 0.f, a4 = 0.f, a5 = 0.f, a6 = 0.f, a7 = 0.f;
  int e0 = 0, e1 = 0; float di = 0.f;
  if (node < N) {
    e0 = rowptr[node]; e1 = rowptr[node + 1]; di = dinv[node];
    uint4 u = ((const uint4*)hin)[(size_t)node * 16 + l16];
    ADD8(u);
  }
  int eb = rowptr[row0];
  int ee = rowptr[rend];

  // ---- phase 1b ----
  for (int c0 = eb; c0 < ee; c0 += CH) {
    if (tid < CH) {
      int e = c0 + tid;
      smcol[tid] = (e < ee) ? col[e] : 0;
    }
    __syncthreads();
#pragma unroll
    for (int q = 0; q < 3; ++q) {
      int slb = wv * 12 + q * 4;
      int row = smcol[slb + (lane >> 4)];
      const unsigned short* gp = hin + (size_t)row * 128 + (lane & 15) * 8;
      gload_lds16(gp, &stg[slb * 256]);
    }
    __syncthreads();
    int lo = (e0 > c0) ? e0 : c0;
    int hi = (e1 < c0 + CH) ? e1 : (c0 + CH);
    int e2 = lo;
    for (; e2 + 2 <= hi; e2 += 2) {
      int i0 = e2 - c0, i1 = i0 + 1;
      uint4 w0 = *(const uint4*)&stg[i0 * 256 + l16 * 16];
      uint4 w1 = *(const uint4*)&stg[i1 * 256 + l16 * 16];
      ADD8(w0);
      ADD8(w1);
    }
    if (e2 < hi) {
      int i0 = e2 - c0;
      uint4 w0 = *(const uint4*)&stg[i0 * 256 + l16 * 16];
      ADD8(w0);
    }
    __syncthreads();
  }

  // ---- phase 1c: deposit normalized bf16 A-tile ----
  {
    uint4 o;
    o.x = (unsigned int)f2bf(a0 * di) | ((unsigned int)f2bf(a1 * di) << 16);
    o.y = (unsigned int)f2bf(a2 * di) | ((unsigned int)f2bf(a3 * di) << 16);
    o.z = (unsigned int)f2bf(a4 * di) | ((unsigned int)f2bf(a5 * di) << 16);
    o.w = (unsigned int)f2bf(a6 * di) | ((unsigned int)f2bf(a7 * di) << 16);
    *(uint4*)&sm[g * KP + l16 * 8] = o;
  }
  __syncthreads();

  // ---- phase 2 (no epilogue scaling: pool needs raw h3) ----
  int rt = wv & 1, tp = wv >> 1;
  v8s af[KK];
#pragma unroll
  for (int kk = 0; kk < KK; ++kk)
    af[kk] = *(const v8s*)&sm[(rt * 16 + l15) * KP + kk * 32 + quad * 8];
  __syncthreads();

#pragma unroll
  for (int tt = 0; tt < 2; ++tt) {
    int t = tp * 2 + tt;
    v4f acc = {0.f, 0.f, 0.f, 0.f};
#pragma unroll
    for (int kk = 0; kk < KK; ++kk) {
      v8s bf = *(const v8s*)(WTF + (size_t)(((t * KK + kk) * 4 + quad) * 16 + l15) * 8);
      acc = __builtin_amdgcn_mfma_f32_16x16x32_bf16(af[kk], bf, acc, 0, 0, 0);
    }
    float bias = b[t * 16 + l15];
#pragma unroll
    for (int i = 0; i < 4; ++i) {
      float o = fmaxf(acc[i] + bias, 0.f);
      sm[(rt * 16 + quad * 4 + i) * CP + t * 16 + l15] = f2bf(o);
    }
  }
  __syncthreads();

  // ---- phase 3: segment-sum the 32 sorted rows, atomicAdd partials ----
  int f = tid & 127;
  int grp = tid >> 7;               // 4 groups x 8 rows
  float run = 0.f;
  int cur = -1;
#pragma unroll
  for (int j = 0; j < 8; ++j) {
    int r = grp * 8 + j;
    int gg = sbatch[r];
    if (gg != cur) {
      if (cur >= 0) atomicAdd(&out[(size_t)cur * 128 + f], run);
      run = 0.f; cur = gg;
    }
    if (gg >= 0) run += bf2f(sm[r * CP + f]);
  }
  if (cur >= 0) atomicAdd(&out[(size_t)cur * 128 + f], run);
}

// divide pooled sums by segment counts
__global__ void k_finalize(float* __restrict__ out, const int* __restrict__ gstart, int G) {
  int idx = blockIdx.x * blockDim.x + threadIdx.x;
  if (idx >= G * 128) return;
  int g = idx >> 7;
  float cnt = (float)(gstart[g + 1] - gstart[g]);
  out[idx] = out[idx] / fmaxf(cnt, 1.f);
}

extern "C" void kernel_launch(void* const* d_in, const int* in_sizes, int n_in,
                              void* d_out, int out_size, void* d_ws, size_t ws_size,
                              hipStream_t stream) {
  const float* x  = (const float*)d_in[0];
  const int* ei   = (const int*)d_in[1];
  const int* batch = (const int*)d_in[2];
  const float* W1 = (const float*)d_in[3];
  const float* b1 = (const float*)d_in[4];
  const float* W2 = (const float*)d_in[5];
  const float* b2 = (const float*)d_in[6];
  const float* W3 = (const float*)d_in[7];
  const float* b3 = (const float*)d_in[8];
  float* out = (float*)d_out;
  int N = in_sizes[2];
  int E = in_sizes[1] / 2;
  int G = out_size / HD;
  const int* src = ei;
  const int* dst = ei + E;

  size_t off = 0;
  char* ws = (char*)d_ws;
  auto alloc = [&](size_t bytes) -> void* {
    void* p = ws + off;
    off += (bytes + 255) & ~(size_t)255;
    return p;
  };
  int nb1024 = (N + 1023) / 1024;
  int*   deg     = (int*)alloc((size_t)N * 4);
  int*   scanbuf = (int*)alloc((size_t)nb1024 * 4);   // contiguous after deg -> one memset
  float* dinv    = (float*)alloc((size_t)N * 4);
  int*   rowptr  = (int*)alloc((size_t)(N + 1) * 4);
  int*   eord    = (int*)alloc((size_t)E * 4);
  int*   col     = (int*)alloc((size_t)E * 4);
  int*   gstart  = (int*)alloc((size_t)(G + 1) * 4);
  unsigned short* xb = (unsigned short*)alloc((size_t)N * 32 * 2);
  unsigned short* hA = (unsigned short*)alloc((size_t)N * HD * 2);
  unsigned short* hB = (unsigned short*)alloc((size_t)N * HD * 2);
  unsigned short* W1F = (unsigned short*)alloc(4096 * 2);
  unsigned short* W2F = (unsigned short*)alloc(16384 * 2);
  unsigned short* W3F = (unsigned short*)alloc(16384 * 2);
  (void)ws_size; (void)n_in;

  size_t zbytes = (size_t)((char*)dinv - (char*)deg);  // deg + scanbuf region
  hipMemsetAsync(deg, 0, zbytes, stream);
  k_degree<<<(E + 255) / 256, 256, 0, stream>>>(dst, deg, eord, E);
  k_scan<<<nb1024, 256, 0, stream>>>(deg, scanbuf, rowptr, dinv, N);

  int SB = (E + 255) / 256;
  int XB = (N * 32 + 255) / 256;
  int WB = 144;
  int BB = (N + 255) / 256;
  int ZB = (G * 32 + 255) / 256;   // out zero, float4/thread
  k_prep<<<SB + XB + WB + BB + ZB, 256, 0, stream>>>(src, dst, rowptr, eord, col, E,
                                                     x, dinv, xb, N,
                                                     W1, W2, W3, W1F, W2F, W3F,
                                                     batch, gstart, G, out,
                                                     SB, XB, WB, BB);

  int fusedBlocks = (N + 31) / 32;
  k_fused<32><<<fusedBlocks, 512, 0, stream>>>(xb, W1F, b1, rowptr, col, dinv, hA, N);
  k_fused<128><<<fusedBlocks, 512, 0, stream>>>(hA, W2F, b2, rowptr, col, dinv, hB, N);
  k_fused_pool<<<fusedBlocks, 512, 0, stream>>>(hB, W3F, b3, rowptr, col, dinv, batch, out, N);
  k_finalize<<<(G * 128 + 255) / 256, 256, 0, stream>>>(out, gstart, G);
}

// Round 13
// 248.673 us; speedup vs baseline: 1.4171x; 1.0314x over previous
//
#include <hip/hip_runtime.h>

// 3-layer GCN + mean pool. MFMA GEMM / fp32 accumulate / bf16 interchange.
// R25: continue R24's confirmed lever (block-level drain overlap).
// R24 proved it: 2 resident blocks/CU -> 62us/layer, 4 -> 53us (-15%),
// the only axis that EVER moved the wall (bytes/MLP/randomness/inst-count
// all null, R14-R23). This round: 256-thr/4-wave/16-node blocks, CH=48
// -> LDS ~17KB -> 8 resident blocks/CU (wave-capped), 2x overlap depth,
// avg block (48 edges) stages in ONE chunk -> one drain per block.
// All staging (global_load_lds w16) / reduce (bf16 sum) / MFMA / epilogue
// logic identical to R24, re-indexed for 16 nodes.

#define DIN 30
#define HD  128

typedef __attribute__((ext_vector_type(8))) short v8s;
typedef __attribute__((ext_vector_type(4))) float v4f;

static __device__ __forceinline__ unsigned short f2bf(float f) {
  unsigned int u = __float_as_uint(f);
  u += 0x7fffu + ((u >> 16) & 1u);   // RNE
  return (unsigned short)(u >> 16);
}
static __device__ __forceinline__ float bf2f(unsigned short s) {
  return __uint_as_float(((unsigned int)s) << 16);
}
static __device__ __forceinline__ float bflo(unsigned int u) {
  return __uint_as_float(u << 16);
}
static __device__ __forceinline__ float bfhi(unsigned int u) {
  return __uint_as_float(u & 0xffff0000u);
}

// async global->LDS, 16B per lane; LDS dest is wave-uniform base + lane*16
static __device__ __forceinline__ void gload_lds16(const void* g, void* l) {
  __builtin_amdgcn_global_load_lds(
      (const __attribute__((address_space(1))) void*)g,
      (__attribute__((address_space(3))) void*)l, 16, 0, 0);
}

// sum 8 bf16 (uint4) into a0..a7
#define ADD8(v)                          \
  {                                      \
    a0 += bflo((v).x); a1 += bfhi((v).x); \
    a2 += bflo((v).y); a3 += bfhi((v).y); \
    a4 += bflo((v).z); a5 += bfhi((v).z); \
    a6 += bflo((v).w); a7 += bfhi((v).w); \
  }

// ---------------- preprocessing ----------------
__global__ void k_degree(const int* __restrict__ dst, int* __restrict__ deg,
                         int* __restrict__ eord, int E) {
  int e = blockIdx.x * blockDim.x + threadIdx.x;
  if (e < E) eord[e] = atomicAdd(&deg[dst[e]], 1);
}

// single-dispatch exclusive scan (decoupled lookback, flag bit 31) + dinv.
__global__ void k_scan(const int* __restrict__ deg, int* __restrict__ scanbuf,
                       int* __restrict__ rowptr, float* __restrict__ dinv, int N) {
  __shared__ int s[256];
  __shared__ int sbase;
  int bid = blockIdx.x, tid = threadIdx.x;
  int base = bid * 1024 + tid * 4;
  int v[4]; int t = 0;
#pragma unroll
  for (int j = 0; j < 4; ++j) { int idx = base + j; v[j] = (idx < N) ? deg[idx] : 0; t += v[j]; }
  s[tid] = t; __syncthreads();
  for (int d = 1; d < 256; d <<= 1) {
    int u = (tid >= d) ? s[tid - d] : 0;
    __syncthreads();
    s[tid] += u;
    __syncthreads();
  }
  int myexcl = s[tid] - t;
  int blocktotal = s[255];
  if (tid == 0) atomicExch(&scanbuf[bid], blocktotal | 0x80000000);

  int pre = 0;
  for (int p = tid; p < bid; p += 256) {
    int val;
    do { val = atomicAdd(&scanbuf[p], 0); } while (!(val & 0x80000000));
    pre += val & 0x7fffffff;
  }
  __syncthreads();
  s[tid] = pre; __syncthreads();
  for (int d = 128; d > 0; d >>= 1) { if (tid < d) s[tid] += s[tid + d]; __syncthreads(); }
  if (tid == 0) sbase = s[0];
  __syncthreads();

  int run = sbase + myexcl;
#pragma unroll
  for (int j = 0; j < 4; ++j) {
    int idx = base + j;
    if (idx < N) {
      rowptr[idx] = run;
      dinv[idx] = rsqrtf((float)(1 + v[j]));
    }
    run += v[j];
    if (idx == N - 1) rowptr[N] = run;
  }
}

// fragment-major weight pack helper
static __device__ __forceinline__ void wtf_one(const float* __restrict__ W,
                                               unsigned short* __restrict__ WTF,
                                               int idx, int Kreal, int KK) {
  int j = idx & 7;
  int c = idx >> 3;
  int l15 = c & 15;
  int quad = (c >> 4) & 3;
  int kk = (c >> 6) % KK;
  int t = c / (64 * KK);
  int k = kk * 32 + quad * 8 + j;
  int n = t * 16 + l15;
  WTF[idx] = (k < Kreal) ? f2bf(W[k * 128 + n]) : (unsigned short)0;
}

// merged prep: atomic-free CSR scatter | xcast | wtf | bounds | out-zero
__global__ void k_prep(const int* __restrict__ src, const int* __restrict__ dst,
                       const int* __restrict__ rowptr, const int* __restrict__ eord,
                       int* __restrict__ col, int E,
                       const float* __restrict__ x, const float* __restrict__ dinv,
                       unsigned short* __restrict__ xb, int N,
                       const float* __restrict__ W1, const float* __restrict__ W2,
                       const float* __restrict__ W3,
                       unsigned short* __restrict__ W1F, unsigned short* __restrict__ W2F,
                       unsigned short* __restrict__ W3F,
                       const int* __restrict__ batch, int* __restrict__ gstart, int G,
                       float* __restrict__ out,
                       int SB, int XB, int WB, int BB) {
  int blk = blockIdx.x;
  if (blk < SB) {
    int e = blk * 256 + threadIdx.x;
    if (e < E) col[rowptr[dst[e]] + eord[e]] = src[e];
  } else if (blk < SB + XB) {
    int idx = (blk - SB) * 256 + threadIdx.x;
    if (idx < N * 32) {
      int n = idx >> 5, f = idx & 31;
      float v = (f < DIN) ? x[(size_t)n * DIN + f] * dinv[n] : 0.f;
      xb[idx] = f2bf(v);
    }
  } else if (blk < SB + XB + WB) {
    int idx = (blk - SB - XB) * 256 + threadIdx.x;
    if (idx < 4096) wtf_one(W1, W1F, idx, DIN, 1);
    else if (idx < 20480) wtf_one(W2, W2F, idx - 4096, 128, 4);
    else if (idx < 36864) wtf_one(W3, W3F, idx - 20480, 128, 4);
  } else if (blk < SB + XB + WB + BB) {
    int i = (blk - SB - XB - WB) * 256 + threadIdx.x;
    if (i >= N) return;
    int b = batch[i];
    int prev = (i == 0) ? -1 : batch[i - 1];
    for (int g = prev + 1; g <= b; ++g) gstart[g] = i;
    if (i == N - 1)
      for (int g = b + 1; g <= G; ++g) gstart[g] = N;
  } else {
    int idx = (blk - SB - XB - WB - BB) * 256 + threadIdx.x;
    if (idx < G * 32)
      ((float4*)out)[idx] = make_float4(0.f, 0.f, 0.f, 0.f);
  }
}

// ---------------- fused aggregate + MFMA GEMM (layers 1,2) ----------------
// 256 threads / 16 nodes / 4 waves. hin: pre-scaled bf16 rows (K feats).
template <int K>
__global__ __launch_bounds__(256, 8) void k_fused(const unsigned short* __restrict__ hin,
                                                  const unsigned short* __restrict__ WTF,
                                                  const float* __restrict__ b,
                                                  const int* __restrict__ rowptr,
                                                  const int* __restrict__ col,
                                                  const float* __restrict__ dinv,
                                                  unsigned short* __restrict__ C, int N) {
  constexpr int KK = K / 32;
  constexpr int KP = (K == 128) ? 136 : 40;
  constexpr int CP = 132;
  constexpr int SMSZ = (16 * KP > 16 * CP) ? 16 * KP : 16 * CP;
  constexpr int CH = (K == 128) ? 48 : 64;      // edges per staging chunk
  constexpr int RB = K * 2;                     // row bytes
  __shared__ __align__(16) unsigned short sm[SMSZ];
  __shared__ __align__(16) unsigned char stg[CH * RB];
  __shared__ int smcol[CH];

  int tid = threadIdx.x;
  int l16 = tid & 15;
  int g = tid >> 4;                 // 16 groups of 16 lanes
  int lane = tid & 63, wv = tid >> 6, quad = lane >> 4, l15 = lane & 15;
  int row0 = blockIdx.x * 16;
  int node = row0 + g;
  int rend = row0 + 16; if (rend > N) rend = N;

  // ---- phase 1a: self term + ranges ----
  float a0 = 0.f, a1 = 0.f, a2 = 0.f, a3 = 0.f, a4 = 0.f, a5 = 0.f, a6 = 0.f, a7 = 0.f;
  int e0 = 0, e1 = 0; float di = 0.f;
  if (node < N) {
    e0 = rowptr[node]; e1 = rowptr[node + 1]; di = dinv[node];
    if constexpr (K == 32) {
      unsigned int u = ((const unsigned int*)hin)[(size_t)node * 16 + l16];
      a0 = bflo(u); a1 = bfhi(u);
    } else {
      uint4 u = ((const uint4*)hin)[(size_t)node * 16 + l16];
      ADD8(u);
    }
  }
  int eb = rowptr[row0];
  int ee = rowptr[rend];

  // ---- phase 1b: chunked async stage + register sum ----
  for (int c0 = eb; c0 < ee; c0 += CH) {
    if (tid < CH) {
      int e = c0 + tid;
      smcol[tid] = (e < ee) ? col[e] : 0;      // clamp: safe row 0
    }
    __syncthreads();
    if constexpr (K == 128) {
      // wave covers 12 slots (3 issues x 4 slots x 256B); 4 waves x 12 = 48
#pragma unroll
      for (int q = 0; q < 3; ++q) {
        int slb = wv * 12 + q * 4;
        int row = smcol[slb + (lane >> 4)];
        const unsigned short* gp = hin + (size_t)row * 128 + (lane & 15) * 8;
        gload_lds16(gp, &stg[slb * 256]);
      }
    } else {
      // wave covers 16 slots (1 issue x 16 slots x 64B); 4 x 16 = 64
      int slb = wv * 16;
      int row = smcol[slb + (lane >> 2)];
      const unsigned short* gp = hin + (size_t)row * 32 + (lane & 3) * 8;
      gload_lds16(gp, &stg[slb * 64]);
    }
    __syncthreads();                            // drain loads
    int lo = (e0 > c0) ? e0 : c0;
    int hi = (e1 < c0 + CH) ? e1 : (c0 + CH);
    int e2 = lo;
    for (; e2 + 2 <= hi; e2 += 2) {
      int i0 = e2 - c0, i1 = i0 + 1;
      if constexpr (K == 32) {
        unsigned int w0 = *(const unsigned int*)&stg[i0 * 64 + l16 * 4];
        unsigned int w1 = *(const unsigned int*)&stg[i1 * 64 + l16 * 4];
        a0 += bflo(w0); a1 += bfhi(w0);
        a0 += bflo(w1); a1 += bfhi(w1);
      } else {
        uint4 w0 = *(const uint4*)&stg[i0 * 256 + l16 * 16];
        uint4 w1 = *(const uint4*)&stg[i1 * 256 + l16 * 16];
        ADD8(w0);
        ADD8(w1);
      }
    }
    if (e2 < hi) {
      int i0 = e2 - c0;
      if constexpr (K == 32) {
        unsigned int w0 = *(const unsigned int*)&stg[i0 * 64 + l16 * 4];
        a0 += bflo(w0); a1 += bfhi(w0);
      } else {
        uint4 w0 = *(const uint4*)&stg[i0 * 256 + l16 * 16];
        ADD8(w0);
      }
    }
    __syncthreads();                            // protect stg/smcol reuse
  }

  // ---- phase 1c: deposit normalized bf16 A-tile ----
  if constexpr (K == 32) {
    *(unsigned int*)&sm[g * KP + l16 * 2] =
        (unsigned int)f2bf(a0 * di) | ((unsigned int)f2bf(a1 * di) << 16);
  } else {
    uint4 o;
    o.x = (unsigned int)f2bf(a0 * di) | ((unsigned int)f2bf(a1 * di) << 16);
    o.y = (unsigned int)f2bf(a2 * di) | ((unsigned int)f2bf(a3 * di) << 16);
    o.z = (unsigned int)f2bf(a4 * di) | ((unsigned int)f2bf(a5 * di) << 16);
    o.w = (unsigned int)f2bf(a6 * di) | ((unsigned int)f2bf(a7 * di) << 16);
    *(uint4*)&sm[g * KP + l16 * 8] = o;
  }
  __syncthreads();

  // ---- phase 2: A-frags from LDS; 4 waves = 4 t-pairs on one 16-row tile ----
  v8s af[KK];
#pragma unroll
  for (int kk = 0; kk < KK; ++kk)
    af[kk] = *(const v8s*)&sm[l15 * KP + kk * 32 + quad * 8];
  __syncthreads();

  // hoisted next-layer pre-scale: dinv for this lane's 4 output rows
  int crow0 = row0 + quad * 4;
  float dr[4];
  if (crow0 + 3 < N) {
    float4 d4 = *(const float4*)&dinv[crow0];
    dr[0] = d4.x; dr[1] = d4.y; dr[2] = d4.z; dr[3] = d4.w;
  } else {
#pragma unroll
    for (int i = 0; i < 4; ++i) dr[i] = (crow0 + i < N) ? dinv[crow0 + i] : 0.f;
  }

#pragma unroll
  for (int tt = 0; tt < 2; ++tt) {
    int t = wv * 2 + tt;
    v4f acc = {0.f, 0.f, 0.f, 0.f};
#pragma unroll
    for (int kk = 0; kk < KK; ++kk) {
      v8s bf = *(const v8s*)(WTF + (size_t)(((t * KK + kk) * 4 + quad) * 16 + l15) * 8);
      acc = __builtin_amdgcn_mfma_f32_16x16x32_bf16(af[kk], bf, acc, 0, 0, 0);
    }
    float bias = b[t * 16 + l15];
#pragma unroll
    for (int i = 0; i < 4; ++i) {
      float o = fmaxf(acc[i] + bias, 0.f) * dr[i];
      sm[(quad * 4 + i) * CP + t * 16 + l15] = f2bf(o);
    }
  }
  __syncthreads();

  // ---- phase 3: coalesced C store (16 rows x 32 uint2 = 512) ----
#pragma unroll
  for (int j = 0; j < 2; ++j) {
    int linear = j * 256 + tid;
    int r = linear >> 5, ch = linear & 31;
    uint2 v = *(const uint2*)&sm[r * CP + ch * 4];
    int row = row0 + r;
    if (row < N) ((uint2*)C)[(size_t)row * 32 + ch] = v;
  }
}

// ---------------- layer 3: fused aggregate + GEMM + pool-atomics ----------------
__global__ __launch_bounds__(256, 8) void k_fused_pool(const unsigned short* __restrict__ hin,
                                                       const unsigned short* __restrict__ WTF,
                                                       const float* __restrict__ b,
                                                       const int* __restrict__ rowptr,
                                                       const int* __restrict__ col,
                                                       const float* __restrict__ dinv,
                                                       const int* __restrict__ batch,
                                                       float* __restrict__ out, int N) {
  constexpr int KK = 4, KP = 136, CP = 132;
  constexpr int SMSZ = 16 * KP;
  constexpr int CH = 48;
  __shared__ __align__(16) unsigned short sm[SMSZ];
  __shared__ __align__(16) unsigned char stg[CH * 256];
  __shared__ int smcol[CH];
  __shared__ int sbatch[16];

  int tid = threadIdx.x;
  int l16 = tid & 15;
  int g = tid >> 4;
  int lane = tid & 63, wv = tid >> 6, quad = lane >> 4, l15 = lane & 15;
  int row0 = blockIdx.x * 16;
  int node = row0 + g;
  int rend = row0 + 16; if (rend > N) rend = N;

  if (tid < 16) sbatch[tid] = (row0 + tid < N) ? batch[row0 + tid] : -1;

  // ---- phase 1a ----
  float a0 = 0.f, a1 = 0.f, a2 = 0.f, a3 = 0.f, a4 = 0.f, a5 = 0.f, a6 = 0.f, a7 = 0.f;
  int e0 = 0, e1 = 0; float di = 0.f;
  if (node < N) {
    e0 = rowptr[node]; e1 = rowptr[node + 1]; di = dinv[node];
    uint4 u = ((const uint4*)hin)[(size_t)node * 16 + l16];
    ADD8(u);
  }
  int eb = rowptr[row0];
  int ee = rowptr[rend];

  // ---- phase 1b ----
  for (int c0 = eb; c0 < ee; c0 += CH) {
    if (tid < CH) {
      int e = c0 + tid;
      smcol[tid] = (e < ee) ? col[e] : 0;
    }
    __syncthreads();
#pragma unroll
    for (int q = 0; q < 3; ++q) {
      int slb = wv * 12 + q * 4;
      int row = smcol[slb + (lane >> 4)];
      const unsigned short* gp = hin + (size_t)row * 128 + (lane & 15) * 8;
      gload_lds16(gp, &stg[slb * 256]);
    }
    __syncthreads();
    int lo = (e0 > c0) ? e0 : c0;
    int hi = (e1 < c0 + CH) ? e1 : (c0 + CH);
    int e2 = lo;
    for (; e2 + 2 <= hi; e2 += 2) {
      int i0 = e2 - c0, i1 = i0 + 1;
      uint4 w0 = *(const uint4*)&stg[i0 * 256 + l16 * 16];
      uint4 w1 = *(const uint4*)&stg[i1 * 256 + l16 * 16];
      ADD8(w0);
      ADD8(w1);
    }
    if (e2 < hi) {
      int i0 = e2 - c0;
      uint4 w0 = *(const uint4*)&stg[i0 * 256 + l16 * 16];
      ADD8(w0);
    }
    __syncthreads();
  }

  // ---- phase 1c: deposit normalized bf16 A-tile ----
  {
    uint4 o;
    o.x = (unsigned int)f2bf(a0 * di) | ((unsigned int)f2bf(a1 * di) << 16);
    o.y = (unsigned int)f2bf(a2 * di) | ((unsigned int)f2bf(a3 * di) << 16);
    o.z = (unsigned int)f2bf(a4 * di) | ((unsigned int)f2bf(a5 * di) << 16);
    o.w = (unsigned int)f2bf(a6 * di) | ((unsigned int)f2bf(a7 * di) << 16);
    *(uint4*)&sm[g * KP + l16 * 8] = o;
  }
  __syncthreads();

  // ---- phase 2 (no epilogue scaling: pool needs raw h3) ----
  v8s af[KK];
#pragma unroll
  for (int kk = 0; kk < KK; ++kk)
    af[kk] = *(const v8s*)&sm[l15 * KP + kk * 32 + quad * 8];
  __syncthreads();

#pragma unroll
  for (int tt = 0; tt < 2; ++tt) {
    int t = wv * 2 + tt;
    v4f acc = {0.f, 0.f, 0.f, 0.f};
#pragma unroll
    for (int kk = 0; kk < KK; ++kk) {
      v8s bf = *(const v8s*)(WTF + (size_t)(((t * KK + kk) * 4 + quad) * 16 + l15) * 8);
      acc = __builtin_amdgcn_mfma_f32_16x16x32_bf16(af[kk], bf, acc, 0, 0, 0);
    }
    float bias = b[t * 16 + l15];
#pragma unroll
    for (int i = 0; i < 4; ++i) {
      float o = fmaxf(acc[i] + bias, 0.f);
      sm[(quad * 4 + i) * CP + t * 16 + l15] = f2bf(o);
    }
  }
  __syncthreads();

  // ---- phase 3: segment-sum the 16 sorted rows, atomicAdd partials ----
  int f = tid & 127;
  int grp = tid >> 7;               // 2 groups x 8 rows
  float run = 0.f;
  int cur = -1;
#pragma unroll
  for (int j = 0; j < 8; ++j) {
    int r = grp * 8 + j;
    int gg = sbatch[r];
    if (gg != cur) {
      if (cur >= 0) atomicAdd(&out[(size_t)cur * 128 + f], run);
      run = 0.f; cur = gg;
    }
    if (gg >= 0) run += bf2f(sm[r * CP + f]);
  }
  if (cur >= 0) atomicAdd(&out[(size_t)cur * 128 + f], run);
}

// divide pooled sums by segment counts
__global__ void k_finalize(float* __restrict__ out, const int* __restrict__ gstart, int G) {
  int idx = blockIdx.x * blockDim.x + threadIdx.x;
  if (idx >= G * 128) return;
  int g = idx >> 7;
  float cnt = (float)(gstart[g + 1] - gstart[g]);
  out[idx] = out[idx] / fmaxf(cnt, 1.f);
}

extern "C" void kernel_launch(void* const* d_in, const int* in_sizes, int n_in,
                              void* d_out, int out_size, void* d_ws, size_t ws_size,
                              hipStream_t stream) {
  const float* x  = (const float*)d_in[0];
  const int* ei   = (const int*)d_in[1];
  const int* batch = (const int*)d_in[2];
  const float* W1 = (const float*)d_in[3];
  const float* b1 = (const float*)d_in[4];
  const float* W2 = (const float*)d_in[5];
  const float* b2 = (const float*)d_in[6];
  const float* W3 = (const float*)d_in[7];
  const float* b3 = (const float*)d_in[8];
  float* out = (float*)d_out;
  int N = in_sizes[2];
  int E = in_sizes[1] / 2;
  int G = out_size / HD;
  const int* src = ei;
  const int* dst = ei + E;

  size_t off = 0;
  char* ws = (char*)d_ws;
  auto alloc = [&](size_t bytes) -> void* {
    void* p = ws + off;
    off += (bytes + 255) & ~(size_t)255;
    return p;
  };
  int nb1024 = (N + 1023) / 1024;
  int*   deg     = (int*)alloc((size_t)N * 4);
  int*   scanbuf = (int*)alloc((size_t)nb1024 * 4);   // contiguous after deg -> one memset
  float* dinv    = (float*)alloc((size_t)N * 4);
  int*   rowptr  = (int*)alloc((size_t)(N + 1) * 4);
  int*   eord    = (int*)alloc((size_t)E * 4);
  int*   col     = (int*)alloc((size_t)E * 4);
  int*   gstart  = (int*)alloc((size_t)(G + 1) * 4);
  unsigned short* xb = (unsigned short*)alloc((size_t)N * 32 * 2);
  unsigned short* hA = (unsigned short*)alloc((size_t)N * HD * 2);
  unsigned short* hB = (unsigned short*)alloc((size_t)N * HD * 2);
  unsigned short* W1F = (unsigned short*)alloc(4096 * 2);
  unsigned short* W2F = (unsigned short*)alloc(16384 * 2);
  unsigned short* W3F = (unsigned short*)alloc(16384 * 2);
  (void)ws_size; (void)n_in;

  size_t zbytes = (size_t)((char*)dinv - (char*)deg);  // deg + scanbuf region
  hipMemsetAsync(deg, 0, zbytes, stream);
  k_degree<<<(E + 255) / 256, 256, 0, stream>>>(dst, deg, eord, E);
  k_scan<<<nb1024, 256, 0, stream>>>(deg, scanbuf, rowptr, dinv, N);

  int SB = (E + 255) / 256;
  int XB = (N * 32 + 255) / 256;
  int WB = 144;
  int BB = (N + 255) / 256;
  int ZB = (G * 32 + 255) / 256;   // out zero, float4/thread
  k_prep<<<SB + XB + WB + BB + ZB, 256, 0, stream>>>(src, dst, rowptr, eord, col, E,
                                                     x, dinv, xb, N,
                                                     W1, W2, W3, W1F, W2F, W3F,
                                                     batch, gstart, G, out,
                                                     SB, XB, WB, BB);

  int fusedBlocks = (N + 15) / 16;
  k_fused<32><<<fusedBlocks, 256, 0, stream>>>(xb, W1F, b1, rowptr, col, dinv, hA, N);
  k_fused<128><<<fusedBlocks, 256, 0, stream>>>(hA, W2F, b2, rowptr, col, dinv, hB, N);
  k_fused_pool<<<fusedBlocks, 256, 0, stream>>>(hB, W3F, b3, rowptr, col, dinv, batch, out, N);
  k_finalize<<<(G * 128 + 255) / 256, 256, 0, stream>>>(out, gstart, G);
}

// Round 14
// 237.536 us; speedup vs baseline: 1.4835x; 1.0469x over previous
//
#include <hip/hip_runtime.h>

// 3-layer GCN + mean pool. MFMA GEMM / fp32 accumulate.
// R26: uint8 interchange RE-TESTED on the saturated-overlap structure.
// R24/R25 proved block-overlap was the wall (2->62us, 4->53, 8->52,
// saturated). R16's "uint8 null" verdict was measured in the 2-block
// latency regime and doesn't transfer. At saturation the candidate
// limiter is random line service (bf16 row = 256B = 2 lines/gather,
// 2.25 TB/s effective). This round:
//  - inter-layer tables uint8 + per-row fp32 scale (128B = 1 line/row),
//    R16's proven quantize/dequant, on R25's 256-thr/8-block structure
//  - scales staged same-thread with smcol (L2-resident 800KB array)
//  - staging stays global_load_lds w16 (8 lanes x 16B per slot)
//  - xcast vectorized 8 bf16/thread (25000 -> 3125 blocks)
// If FETCH halves and dur doesn't move: structural floor -> ROOFLINE.

#define DIN 30
#define HD  128

typedef __attribute__((ext_vector_type(8))) short v8s;
typedef __attribute__((ext_vector_type(4))) float v4f;

static __device__ __forceinline__ unsigned short f2bf(float f) {
  unsigned int u = __float_as_uint(f);
  u += 0x7fffu + ((u >> 16) & 1u);   // RNE
  return (unsigned short)(u >> 16);
}
static __device__ __forceinline__ float bf2f(unsigned short s) {
  return __uint_as_float(((unsigned int)s) << 16);
}
static __device__ __forceinline__ float bflo(unsigned int u) {
  return __uint_as_float(u << 16);
}
static __device__ __forceinline__ float bfhi(unsigned int u) {
  return __uint_as_float(u & 0xffff0000u);
}

// async global->LDS, 16B per lane; LDS dest is wave-uniform base + lane*16
static __device__ __forceinline__ void gload_lds16(const void* g, void* l) {
  __builtin_amdgcn_global_load_lds(
      (const __attribute__((address_space(1))) void*)g,
      (__attribute__((address_space(3))) void*)l, 16, 0, 0);
}

// dequant-accumulate 8 uint8 feats (uint2) scaled by s into a0..a7
#define ACC8(v, s)                                            \
  {                                                           \
    a0 += (s) * (float)((v).x & 0xffu);                       \
    a1 += (s) * (float)(((v).x >> 8) & 0xffu);                \
    a2 += (s) * (float)(((v).x >> 16) & 0xffu);               \
    a3 += (s) * (float)((v).x >> 24);                         \
    a4 += (s) * (float)((v).y & 0xffu);                       \
    a5 += (s) * (float)(((v).y >> 8) & 0xffu);                \
    a6 += (s) * (float)(((v).y >> 16) & 0xffu);               \
    a7 += (s) * (float)((v).y >> 24);                         \
  }

// ---------------- preprocessing ----------------
__global__ void k_degree(const int* __restrict__ dst, int* __restrict__ deg,
                         int* __restrict__ eord, int E) {
  int e = blockIdx.x * blockDim.x + threadIdx.x;
  if (e < E) eord[e] = atomicAdd(&deg[dst[e]], 1);
}

// single-dispatch exclusive scan (decoupled lookback, flag bit 31) + dinv.
__global__ void k_scan(const int* __restrict__ deg, int* __restrict__ scanbuf,
                       int* __restrict__ rowptr, float* __restrict__ dinv, int N) {
  __shared__ int s[256];
  __shared__ int sbase;
  int bid = blockIdx.x, tid = threadIdx.x;
  int base = bid * 1024 + tid * 4;
  int v[4]; int t = 0;
#pragma unroll
  for (int j = 0; j < 4; ++j) { int idx = base + j; v[j] = (idx < N) ? deg[idx] : 0; t += v[j]; }
  s[tid] = t; __syncthreads();
  for (int d = 1; d < 256; d <<= 1) {
    int u = (tid >= d) ? s[tid - d] : 0;
    __syncthreads();
    s[tid] += u;
    __syncthreads();
  }
  int myexcl = s[tid] - t;
  int blocktotal = s[255];
  if (tid == 0) atomicExch(&scanbuf[bid], blocktotal | 0x80000000);

  int pre = 0;
  for (int p = tid; p < bid; p += 256) {
    int val;
    do { val = atomicAdd(&scanbuf[p], 0); } while (!(val & 0x80000000));
    pre += val & 0x7fffffff;
  }
  __syncthreads();
  s[tid] = pre; __syncthreads();
  for (int d = 128; d > 0; d >>= 1) { if (tid < d) s[tid] += s[tid + d]; __syncthreads(); }
  if (tid == 0) sbase = s[0];
  __syncthreads();

  int run = sbase + myexcl;
#pragma unroll
  for (int j = 0; j < 4; ++j) {
    int idx = base + j;
    if (idx < N) {
      rowptr[idx] = run;
      dinv[idx] = rsqrtf((float)(1 + v[j]));
    }
    run += v[j];
    if (idx == N - 1) rowptr[N] = run;
  }
}

// fragment-major weight pack helper
static __device__ __forceinline__ void wtf_one(const float* __restrict__ W,
                                               unsigned short* __restrict__ WTF,
                                               int idx, int Kreal, int KK) {
  int j = idx & 7;
  int c = idx >> 3;
  int l15 = c & 15;
  int quad = (c >> 4) & 3;
  int kk = (c >> 6) % KK;
  int t = c / (64 * KK);
  int k = kk * 32 + quad * 8 + j;
  int n = t * 16 + l15;
  WTF[idx] = (k < Kreal) ? f2bf(W[k * 128 + n]) : (unsigned short)0;
}

// merged prep: atomic-free CSR scatter | xcast(8/thread) | wtf | bounds | out-zero
__global__ void k_prep(const int* __restrict__ src, const int* __restrict__ dst,
                       const int* __restrict__ rowptr, const int* __restrict__ eord,
                       int* __restrict__ col, int E,
                       const float* __restrict__ x, const float* __restrict__ dinv,
                       unsigned short* __restrict__ xb, int N,
                       const float* __restrict__ W1, const float* __restrict__ W2,
                       const float* __restrict__ W3,
                       unsigned short* __restrict__ W1F, unsigned short* __restrict__ W2F,
                       unsigned short* __restrict__ W3F,
                       const int* __restrict__ batch, int* __restrict__ gstart, int G,
                       float* __restrict__ out,
                       int SB, int XB, int WB, int BB) {
  int blk = blockIdx.x;
  if (blk < SB) {
    int e = blk * 256 + threadIdx.x;
    if (e < E) col[rowptr[dst[e]] + eord[e]] = src[e];
  } else if (blk < SB + XB) {
    int idx = (blk - SB) * 256 + threadIdx.x;
    if (idx < N * 4) {
      int n = idx >> 2, s4 = idx & 3, f0 = s4 * 8;
      float di = dinv[n];
      unsigned int w[4];
#pragma unroll
      for (int j = 0; j < 8; j += 2) {
        int f = f0 + j;
        float v0 = (f < DIN) ? x[(size_t)n * DIN + f] * di : 0.f;
        float v1 = (f + 1 < DIN) ? x[(size_t)n * DIN + f + 1] * di : 0.f;
        w[j >> 1] = (unsigned int)f2bf(v0) | ((unsigned int)f2bf(v1) << 16);
      }
      uint4 o; o.x = w[0]; o.y = w[1]; o.z = w[2]; o.w = w[3];
      ((uint4*)xb)[idx] = o;
    }
  } else if (blk < SB + XB + WB) {
    int idx = (blk - SB - XB) * 256 + threadIdx.x;
    if (idx < 4096) wtf_one(W1, W1F, idx, DIN, 1);
    else if (idx < 20480) wtf_one(W2, W2F, idx - 4096, 128, 4);
    else if (idx < 36864) wtf_one(W3, W3F, idx - 20480, 128, 4);
  } else if (blk < SB + XB + WB + BB) {
    int i = (blk - SB - XB - WB) * 256 + threadIdx.x;
    if (i >= N) return;
    int b = batch[i];
    int prev = (i == 0) ? -1 : batch[i - 1];
    for (int g = prev + 1; g <= b; ++g) gstart[g] = i;
    if (i == N - 1)
      for (int g = b + 1; g <= G; ++g) gstart[g] = N;
  } else {
    int idx = (blk - SB - XB - WB - BB) * 256 + threadIdx.x;
    if (idx < G * 32)
      ((float4*)out)[idx] = make_float4(0.f, 0.f, 0.f, 0.f);
  }
}

// ---------------- fused aggregate + MFMA GEMM (layers 1,2) ----------------
// 256 threads / 16 nodes / 4 waves.
// K=32: input bf16 xb (64B rows). K=128: input uint8 rows (128B) + scale.
// Output: uint8 rows + per-row scale (next-layer dinv pre-folded).
template <int K>
__global__ __launch_bounds__(256, 8) void k_fused(const void* __restrict__ hin,
                                                  const float* __restrict__ hscale,
                                                  const unsigned short* __restrict__ WTF,
                                                  const float* __restrict__ b,
                                                  const int* __restrict__ rowptr,
                                                  const int* __restrict__ col,
                                                  const float* __restrict__ dinv,
                                                  unsigned char* __restrict__ Cq,
                                                  float* __restrict__ Cs, int N) {
  constexpr int KK = K / 32;
  constexpr int KP = (K == 128) ? 136 : 40;
  constexpr int CP = 132;
  constexpr int SMSZ = (16 * KP > 16 * CP) ? 16 * KP : 16 * CP;
  constexpr int CH = 64;                        // edges per staging chunk
  constexpr int RB = (K == 128) ? 128 : 64;     // staged row bytes
  __shared__ __align__(16) unsigned short sm[SMSZ];
  __shared__ __align__(16) unsigned char stg[CH * RB];
  __shared__ int smcol[CH];
  __shared__ float sscale[(K == 128) ? CH : 1];

  int tid = threadIdx.x;
  int l16 = tid & 15;
  int g = tid >> 4;                 // 16 groups of 16 lanes
  int lane = tid & 63, wv = tid >> 6, quad = lane >> 4, l15 = lane & 15;
  int row0 = blockIdx.x * 16;
  int node = row0 + g;
  int rend = row0 + 16; if (rend > N) rend = N;

  // ---- phase 1a: self term + ranges ----
  float a0 = 0.f, a1 = 0.f, a2 = 0.f, a3 = 0.f, a4 = 0.f, a5 = 0.f, a6 = 0.f, a7 = 0.f;
  int e0 = 0, e1 = 0; float di = 0.f;
  if (node < N) {
    e0 = rowptr[node]; e1 = rowptr[node + 1]; di = dinv[node];
    if constexpr (K == 32) {
      unsigned int u = ((const unsigned int*)hin)[(size_t)node * 16 + l16];
      a0 = bflo(u); a1 = bfhi(u);
    } else {
      uint2 u = ((const uint2*)hin)[(size_t)node * 16 + l16];
      float s = hscale[node];
      ACC8(u, s);
    }
  }
  int eb = rowptr[row0];
  int ee = rowptr[rend];

  // ---- phase 1b: chunked async stage + register reduce ----
  for (int c0 = eb; c0 < ee; c0 += CH) {
    if (tid < CH) {
      int e = c0 + tid;
      int c = (e < ee) ? col[e] : 0;           // clamp: safe row 0
      smcol[tid] = c;
      if constexpr (K == 128) sscale[tid] = hscale[c];
    }
    __syncthreads();
    if constexpr (K == 128) {
      // wave covers 16 slots (2 issues x 8 slots x 128B); 4 waves x 16 = 64
#pragma unroll
      for (int q = 0; q < 2; ++q) {
        int slb = wv * 16 + q * 8;
        int row = smcol[slb + (lane >> 3)];
        const unsigned char* gp = (const unsigned char*)hin + (size_t)row * 128 + (lane & 7) * 16;
        gload_lds16(gp, &stg[slb * 128]);
      }
    } else {
      // wave covers 16 slots (1 issue x 16 slots x 64B); 4 x 16 = 64
      int slb = wv * 16;
      int row = smcol[slb + (lane >> 2)];
      const unsigned short* gp = (const unsigned short*)hin + (size_t)row * 32 + (lane & 3) * 8;
      gload_lds16(gp, &stg[slb * 64]);
    }
    __syncthreads();                            // drain loads
    int lo = (e0 > c0) ? e0 : c0;
    int hi = (e1 < c0 + CH) ? e1 : (c0 + CH);
    int e2 = lo;
    for (; e2 + 2 <= hi; e2 += 2) {
      int i0 = e2 - c0, i1 = i0 + 1;
      if constexpr (K == 32) {
        unsigned int w0 = *(const unsigned int*)&stg[i0 * 64 + l16 * 4];
        unsigned int w1 = *(const unsigned int*)&stg[i1 * 64 + l16 * 4];
        a0 += bflo(w0); a1 += bfhi(w0);
        a0 += bflo(w1); a1 += bfhi(w1);
      } else {
        uint2 w0 = *(const uint2*)&stg[i0 * 128 + l16 * 8];
        uint2 w1 = *(const uint2*)&stg[i1 * 128 + l16 * 8];
        float s0 = sscale[i0], s1 = sscale[i1];
        ACC8(w0, s0);
        ACC8(w1, s1);
      }
    }
    if (e2 < hi) {
      int i0 = e2 - c0;
      if constexpr (K == 32) {
        unsigned int w0 = *(const unsigned int*)&stg[i0 * 64 + l16 * 4];
        a0 += bflo(w0); a1 += bfhi(w0);
      } else {
        uint2 w0 = *(const uint2*)&stg[i0 * 128 + l16 * 8];
        float s0 = sscale[i0];
        ACC8(w0, s0);
      }
    }
    __syncthreads();                            // protect stg/smcol reuse
  }

  // ---- phase 1c: deposit normalized bf16 A-tile ----
  if constexpr (K == 32) {
    *(unsigned int*)&sm[g * KP + l16 * 2] =
        (unsigned int)f2bf(a0 * di) | ((unsigned int)f2bf(a1 * di) << 16);
  } else {
    uint4 o;
    o.x = (unsigned int)f2bf(a0 * di) | ((unsigned int)f2bf(a1 * di) << 16);
    o.y = (unsigned int)f2bf(a2 * di) | ((unsigned int)f2bf(a3 * di) << 16);
    o.z = (unsigned int)f2bf(a4 * di) | ((unsigned int)f2bf(a5 * di) << 16);
    o.w = (unsigned int)f2bf(a6 * di) | ((unsigned int)f2bf(a7 * di) << 16);
    *(uint4*)&sm[g * KP + l16 * 8] = o;
  }
  __syncthreads();

  // ---- phase 2: A-frags from LDS; 4 waves = 4 t-pairs on one 16-row tile ----
  v8s af[KK];
#pragma unroll
  for (int kk = 0; kk < KK; ++kk)
    af[kk] = *(const v8s*)&sm[l15 * KP + kk * 32 + quad * 8];
  __syncthreads();

  // hoisted next-layer pre-scale: dinv for this lane's 4 output rows
  int crow0 = row0 + quad * 4;
  float dr[4];
  if (crow0 + 3 < N) {
    float4 d4 = *(const float4*)&dinv[crow0];
    dr[0] = d4.x; dr[1] = d4.y; dr[2] = d4.z; dr[3] = d4.w;
  } else {
#pragma unroll
    for (int i = 0; i < 4; ++i) dr[i] = (crow0 + i < N) ? dinv[crow0 + i] : 0.f;
  }

#pragma unroll
  for (int tt = 0; tt < 2; ++tt) {
    int t = wv * 2 + tt;
    v4f acc = {0.f, 0.f, 0.f, 0.f};
#pragma unroll
    for (int kk = 0; kk < KK; ++kk) {
      v8s bf = *(const v8s*)(WTF + (size_t)(((t * KK + kk) * 4 + quad) * 16 + l15) * 8);
      acc = __builtin_amdgcn_mfma_f32_16x16x32_bf16(af[kk], bf, acc, 0, 0, 0);
    }
    float bias = b[t * 16 + l15];
#pragma unroll
    for (int i = 0; i < 4; ++i) {
      float o = fmaxf(acc[i] + bias, 0.f) * dr[i];
      sm[(quad * 4 + i) * CP + t * 16 + l15] = f2bf(o);
    }
  }
  __syncthreads();

  // ---- phase 3: per-row uint8 quantize + coalesced store ----
  {
    uint4 u = *(const uint4*)&sm[g * CP + l16 * 8];
    float f0 = bflo(u.x), f1 = bfhi(u.x), f2 = bflo(u.y), f3 = bfhi(u.y);
    float f4 = bflo(u.z), f5 = bfhi(u.z), f6 = bflo(u.w), f7 = bfhi(u.w);
    float m = fmaxf(fmaxf(fmaxf(f0, f1), fmaxf(f2, f3)),
                    fmaxf(fmaxf(f4, f5), fmaxf(f6, f7)));
    m = fmaxf(m, __shfl_xor(m, 1));
    m = fmaxf(m, __shfl_xor(m, 2));
    m = fmaxf(m, __shfl_xor(m, 4));
    m = fmaxf(m, __shfl_xor(m, 8));
    float inv = (m > 0.f) ? 255.f / m : 0.f;
    unsigned q0 = (unsigned)__float2int_rn(fminf(f0 * inv, 255.f));
    unsigned q1 = (unsigned)__float2int_rn(fminf(f1 * inv, 255.f));
    unsigned q2 = (unsigned)__float2int_rn(fminf(f2 * inv, 255.f));
    unsigned q3 = (unsigned)__float2int_rn(fminf(f3 * inv, 255.f));
    unsigned q4 = (unsigned)__float2int_rn(fminf(f4 * inv, 255.f));
    unsigned q5 = (unsigned)__float2int_rn(fminf(f5 * inv, 255.f));
    unsigned q6 = (unsigned)__float2int_rn(fminf(f6 * inv, 255.f));
    unsigned q7 = (unsigned)__float2int_rn(fminf(f7 * inv, 255.f));
    uint2 o;
    o.x = q0 | (q1 << 8) | (q2 << 16) | (q3 << 24);
    o.y = q4 | (q5 << 8) | (q6 << 16) | (q7 << 24);
    int row = row0 + g;
    if (row < N) {
      ((uint2*)Cq)[(size_t)row * 16 + l16] = o;
      if (l16 == 0) Cs[row] = m * (1.f / 255.f);
    }
  }
}

// ---------------- layer 3: fused aggregate + GEMM + pool-atomics ----------------
__global__ __launch_bounds__(256, 8) void k_fused_pool(const unsigned char* __restrict__ hin,
                                                       const float* __restrict__ hscale,
                                                       const unsigned short* __restrict__ WTF,
                                                       const float* __restrict__ b,
                                                       const int* __restrict__ rowptr,
                                                       const int* __restrict__ col,
                                                       const float* __restrict__ dinv,
                                                       const int* __restrict__ batch,
                                                       float* __restrict__ out, int N) {
  constexpr int KK = 4, KP = 136, CP = 132;
  constexpr int SMSZ = 16 * KP;
  constexpr int CH = 64;
  __shared__ __align__(16) unsigned short sm[SMSZ];
  __shared__ __align__(16) unsigned char stg[CH * 128];
  __shared__ int smcol[CH];
  __shared__ float sscale[CH];
  __shared__ int sbatch[16];

  int tid = threadIdx.x;
  int l16 = tid & 15;
  int g = tid >> 4;
  int lane = tid & 63, wv = tid >> 6, quad = lane >> 4, l15 = lane & 15;
  int row0 = blockIdx.x * 16;
  int node = row0 + g;
  int rend = row0 + 16; if (rend > N) rend = N;

  if (tid < 16) sbatch[tid] = (row0 + tid < N) ? batch[row0 + tid] : -1;

  // ---- phase 1a ----
  float a0 = 0.f, a1 = 0.f, a2 = 0.f, a3 = 0.f, a4 = 0.f, a5 = 0.f, a6 = 0.f, a7 = 0.f;
  int e0 = 0, e1 = 0; float di = 0.f;
  if (node < N) {
    e0 = rowptr[node]; e1 = rowptr[node + 1]; di = dinv[node];
    uint2 u = ((const uint2*)hin)[(size_t)node * 16 + l16];
    float s = hscale[node];
    ACC8(u, s);
  }
  int eb = rowptr[row0];
  int ee = rowptr[rend];

  // ---- phase 1b ----
  for (int c0 = eb; c0 < ee; c0 += CH) {
    if (tid < CH) {
      int e = c0 + tid;
      int c = (e < ee) ? col[e] : 0;
      smcol[tid] = c;
      sscale[tid] = hscale[c];
    }
    __syncthreads();
#pragma unroll
    for (int q = 0; q < 2; ++q) {
      int slb = wv * 16 + q * 8;
      int row = smcol[slb + (lane >> 3)];
      const unsigned char* gp = hin + (size_t)row * 128 + (lane & 7) * 16;
      gload_lds16(gp, &stg[slb * 128]);
    }
    __syncthreads();
    int lo = (e0 > c0) ? e0 : c0;
    int hi = (e1 < c0 + CH) ? e1 : (c0 + CH);
    int e2 = lo;
    for (; e2 + 2 <= hi; e2 += 2) {
      int i0 = e2 - c0, i1 = i0 + 1;
      uint2 w0 = *(const uint2*)&stg[i0 * 128 + l16 * 8];
      uint2 w1 = *(const uint2*)&stg[i1 * 128 + l16 * 8];
      float s0 = sscale[i0], s1 = sscale[i1];
      ACC8(w0, s0);
      ACC8(w1, s1);
    }
    if (e2 < hi) {
      int i0 = e2 - c0;
      uint2 w0 = *(const uint2*)&stg[i0 * 128 + l16 * 8];
      float s0 = sscale[i0];
      ACC8(w0, s0);
    }
    __syncthreads();
  }

  // ---- phase 1c: deposit normalized bf16 A-tile ----
  {
    uint4 o;
    o.x = (unsigned int)f2bf(a0 * di) | ((unsigned int)f2bf(a1 * di) << 16);
    o.y = (unsigned int)f2bf(a2 * di) | ((unsigned int)f2bf(a3 * di) << 16);
    o.z = (unsigned int)f2bf(a4 * di) | ((unsigned int)f2bf(a5 * di) << 16);
    o.w = (unsigned int)f2bf(a6 * di) | ((unsigned int)f2bf(a7 * di) << 16);
    *(uint4*)&sm[g * KP + l16 * 8] = o;
  }
  __syncthreads();

  // ---- phase 2 (no epilogue scaling: pool needs raw h3) ----
  v8s af[KK];
#pragma unroll
  for (int kk = 0; kk < KK; ++kk)
    af[kk] = *(const v8s*)&sm[l15 * KP + kk * 32 + quad * 8];
  __syncthreads();

#pragma unroll
  for (int tt = 0; tt < 2; ++tt) {
    int t = wv * 2 + tt;
    v4f acc = {0.f, 0.f, 0.f, 0.f};
#pragma unroll
    for (int kk = 0; kk < KK; ++kk) {
      v8s bf = *(const v8s*)(WTF + (size_t)(((t * KK + kk) * 4 + quad) * 16 + l15) * 8);
      acc = __builtin_amdgcn_mfma_f32_16x16x32_bf16(af[kk], bf, acc, 0, 0, 0);
    }
    float bias = b[t * 16 + l15];
#pragma unroll
    for (int i = 0; i < 4; ++i) {
      float o = fmaxf(acc[i] + bias, 0.f);
      sm[(quad * 4 + i) * CP + t * 16 + l15] = f2bf(o);
    }
  }
  __syncthreads();

  // ---- phase 3: segment-sum the 16 sorted rows, atomicAdd partials ----
  int f = tid & 127;
  int grp = tid >> 7;               // 2 groups x 8 rows
  float run = 0.f;
  int cur = -1;
#pragma unroll
  for (int j = 0; j < 8; ++j) {
    int r = grp * 8 + j;
    int gg = sbatch[r];
    if (gg != cur) {
      if (cur >= 0) atomicAdd(&out[(size_t)cur * 128 + f], run);
      run = 0.f; cur = gg;
    }
    if (gg >= 0) run += bf2f(sm[r * CP + f]);
  }
  if (cur >= 0) atomicAdd(&out[(size_t)cur * 128 + f], run);
}

// divide pooled sums by segment counts
__global__ void k_finalize(float* __restrict__ out, const int* __restrict__ gstart, int G) {
  int idx = blockIdx.x * blockDim.x + threadIdx.x;
  if (idx >= G * 128) return;
  int g = idx >> 7;
  float cnt = (float)(gstart[g + 1] - gstart[g]);
  out[idx] = out[idx] / fmaxf(cnt, 1.f);
}

extern "C" void kernel_launch(void* const* d_in, const int* in_sizes, int n_in,
                              void* d_out, int out_size, void* d_ws, size_t ws_size,
                              hipStream_t stream) {
  const float* x  = (const float*)d_in[0];
  const int* ei   = (const int*)d_in[1];
  const int* batch = (const int*)d_in[2];
  const float* W1 = (const float*)d_in[3];
  const float* b1 = (const float*)d_in[4];
  const float* W2 = (const float*)d_in[5];
  const float* b2 = (const float*)d_in[6];
  const float* W3 = (const float*)d_in[7];
  const float* b3 = (const float*)d_in[8];
  float* out = (float*)d_out;
  int N = in_sizes[2];
  int E = in_sizes[1] / 2;
  int G = out_size / HD;
  const int* src = ei;
  const int* dst = ei + E;

  size_t off = 0;
  char* ws = (char*)d_ws;
  auto alloc = [&](size_t bytes) -> void* {
    void* p = ws + off;
    off += (bytes + 255) & ~(size_t)255;
    return p;
  };
  int nb1024 = (N + 1023) / 1024;
  int*   deg     = (int*)alloc((size_t)N * 4);
  int*   scanbuf = (int*)alloc((size_t)nb1024 * 4);   // contiguous after deg -> one memset
  float* dinv    = (float*)alloc((size_t)N * 4);
  int*   rowptr  = (int*)alloc((size_t)(N + 1) * 4);
  int*   eord    = (int*)alloc((size_t)E * 4);
  int*   col     = (int*)alloc((size_t)E * 4);
  int*   gstart  = (int*)alloc((size_t)(G + 1) * 4);
  unsigned short* xb  = (unsigned short*)alloc((size_t)N * 32 * 2);
  unsigned char*  hAq = (unsigned char*)alloc((size_t)N * 128);
  float*          hAs = (float*)alloc((size_t)N * 4);
  unsigned char*  hBq = (unsigned char*)alloc((size_t)N * 128);
  float*          hBs = (float*)alloc((size_t)N * 4);
  unsigned short* W1F = (unsigned short*)alloc(4096 * 2);
  unsigned short* W2F = (unsigned short*)alloc(16384 * 2);
  unsigned short* W3F = (unsigned short*)alloc(16384 * 2);
  (void)ws_size; (void)n_in;

  size_t zbytes = (size_t)((char*)dinv - (char*)deg);  // deg + scanbuf region
  hipMemsetAsync(deg, 0, zbytes, stream);
  k_degree<<<(E + 255) / 256, 256, 0, stream>>>(dst, deg, eord, E);
  k_scan<<<nb1024, 256, 0, stream>>>(deg, scanbuf, rowptr, dinv, N);

  int SB = (E + 255) / 256;
  int XB = (N * 4 + 255) / 256;
  int WB = 144;
  int BB = (N + 255) / 256;
  int ZB = (G * 32 + 255) / 256;   // out zero, float4/thread
  k_prep<<<SB + XB + WB + BB + ZB, 256, 0, stream>>>(src, dst, rowptr, eord, col, E,
                                                     x, dinv, xb, N,
                                                     W1, W2, W3, W1F, W2F, W3F,
                                                     batch, gstart, G, out,
                                                     SB, XB, WB, BB);

  int fusedBlocks = (N + 15) / 16;
  k_fused<32><<<fusedBlocks, 256, 0, stream>>>(xb, nullptr, W1F, b1, rowptr, col, dinv,
                                               hAq, hAs, N);
  k_fused<128><<<fusedBlocks, 256, 0, stream>>>(hAq, hAs, W2F, b2, rowptr, col, dinv,
                                                hBq, hBs, N);
  k_fused_pool<<<fusedBlocks, 256, 0, stream>>>(hBq, hBs, W3F, b3, rowptr, col, dinv,
                                                batch, out, N);
  k_finalize<<<(G * 128 + 255) / 256, 256, 0, stream>>>(out, gstart, G);
}